// Round 13
// baseline (1161.228 us; speedup 1.0000x reference)
//
#include <hip/hip_runtime.h>

typedef unsigned short u16;
typedef unsigned int   u32;

#define ACT_NONE 0
#define ACT_RELU 1
#define ACT_TANH 2

#define E_EDGES 500000
#define RP_STRIDE 80004   // per-hop stride for rowptr (ints, 16B-aligned)
#define NCH 62            // edge chunks per hop (8192 edges each)
#define CH 8192
#define HSTRIDE 19456     // per-hop stride in HISTA (>= maxP(313)*NCH(62)=19406)

using s8vec = __attribute__((ext_vector_type(8))) short;   // 8 bf16 (4 VGPRs) MFMA A/B frag
using f4vec = __attribute__((ext_vector_type(4))) float;   // MFMA C/D frag

__device__ __forceinline__ float bf2f(u16 u) {
  union { u32 b; float f; } v; v.b = ((u32)u) << 16; return v.f;
}
__device__ __forceinline__ u16 f2bf(float x) {
  union { float f; u32 b; } v; v.f = x;
  u32 r = v.b + 0x7fffu + ((v.b >> 16) & 1u);   // round-to-nearest-even
  return (u16)(r >> 16);
}
__device__ __forceinline__ void acc8(float* acc, uint4 v) {
  union { u32 b; float f; } cv;
  cv.b = v.x << 16;         acc[0] += cv.f;
  cv.b = v.x & 0xffff0000u; acc[1] += cv.f;
  cv.b = v.y << 16;         acc[2] += cv.f;
  cv.b = v.y & 0xffff0000u; acc[3] += cv.f;
  cv.b = v.z << 16;         acc[4] += cv.f;
  cv.b = v.z & 0xffff0000u; acc[5] += cv.f;
  cv.b = v.w << 16;         acc[6] += cv.f;
  cv.b = v.w & 0xffff0000u; acc[7] += cv.f;
}

// ---------------------------------------------------------------------------
// batched transpose + cast f32->bf16 (+ optional per-row scale): in[R][C]->out[C][R]
struct TJob { const float* src; u16* dst; const float* scale; int R; int C; };
struct TBatch { TJob j[24]; };
__global__ __launch_bounds__(256) void transpose_b_k(TBatch b) {
  TJob jb = b.j[blockIdx.y];
  int i = blockIdx.x * 256 + threadIdx.x;
  if (i >= jb.R * jb.C) return;
  int r = i / jb.C, c = i % jb.C;
  float v = jb.src[i];
  if (jb.scale) v *= jb.scale[r];
  jb.dst[(size_t)c * jb.R + r] = f2bf(v);
}

// ---------------------------------------------------------------------------
// batched inverse permutation: ip[perm[i]] = i
struct IBatch { const int* perm[2]; int* ip[2]; int n[2]; };
__global__ __launch_bounds__(256) void iperm_b_k(IBatch b) {
  int y = blockIdx.y;
  int i = blockIdx.x * 256 + threadIdx.x;
  if (i < b.n[y]) b.ip[y][b.perm[y][i]] = i;
}

// ---------------------------------------------------------------------------
// Two-level bucket CSR build over 14 hops — ZERO global atomics.
struct CsrP { int n[14]; int sh[14]; int P[14]; };

__global__ __launch_bounds__(256) void csr_hist_k(
    const int* __restrict__ eu, const int* __restrict__ ei,
    int* __restrict__ hista, CsrP cp) {
  const int hop = blockIdx.y, chunk = blockIdx.x;
  const int P = cp.P[hop], sh = cp.sh[hop];
  __shared__ int hist[320];
  for (int i = threadIdx.x; i < P; i += 256) hist[i] = 0;
  __syncthreads();
  const int* edges = (hop < 7) ? eu : ei;
  const int h7 = (hop < 7) ? hop : hop - 7;
  const int* dstp = edges + (size_t)(h7 * 2 + 1) * E_EDGES;
  const int e0 = chunk * CH;
  const int e1 = min(E_EDGES, e0 + CH);
  for (int e = e0 + threadIdx.x * 4; e < e1; e += 1024) {
    int4 d4 = *(const int4*)(dstp + e);
    atomicAdd(&hist[d4.x >> sh], 1);
    atomicAdd(&hist[d4.y >> sh], 1);
    atomicAdd(&hist[d4.z >> sh], 1);
    atomicAdd(&hist[d4.w >> sh], 1);
  }
  __syncthreads();
  for (int i = threadIdx.x; i < P; i += 256)
    hista[(size_t)hop * HSTRIDE + i * NCH + chunk] = hist[i];
}

__global__ __launch_bounds__(256) void csr_scan_k(int* __restrict__ hista, CsrP cp) {
  const int hop = blockIdx.x;
  const int L = cp.P[hop] * NCH;
  int* a = hista + (size_t)hop * HSTRIDE;
  const int per = (L + 255) >> 8;
  const int lo = threadIdx.x * per;
  const int hi = min(L, lo + per);
  int s = 0;
  for (int i = lo; i < hi; ++i) s += a[i];
  __shared__ int lds[256];
  lds[threadIdx.x] = s;
  __syncthreads();
  for (int off = 1; off < 256; off <<= 1) {
    int v = (threadIdx.x >= off) ? lds[threadIdx.x - off] : 0;
    __syncthreads();
    lds[threadIdx.x] += v;
    __syncthreads();
  }
  int run = threadIdx.x ? lds[threadIdx.x - 1] : 0;
  for (int i = lo; i < hi; ++i) { int v = a[i]; a[i] = run; run += v; }
}

__global__ __launch_bounds__(256) void csr_scatter_k(
    const int* __restrict__ eu, const int* __restrict__ ei,
    const int* __restrict__ hista, u32* __restrict__ bp, CsrP cp) {
  const int hop = blockIdx.y, chunk = blockIdx.x;
  const int P = cp.P[hop], sh = cp.sh[hop];
  const u32 fm = (1u << sh) - 1u;
  __shared__ int cur[320];
  for (int i = threadIdx.x; i < P; i += 256)
    cur[i] = hista[(size_t)hop * HSTRIDE + i * NCH + chunk];
  __syncthreads();
  const int* edges = (hop < 7) ? eu : ei;
  const int h7 = (hop < 7) ? hop : hop - 7;
  const int* srcp = edges + (size_t)(h7 * 2) * E_EDGES;
  const int* dstp = srcp + E_EDGES;
  u32* b = bp + (size_t)hop * E_EDGES;
  const int e0 = chunk * CH;
  const int e1 = min(E_EDGES, e0 + CH);
  for (int e = e0 + threadIdx.x * 4; e < e1; e += 1024) {
    int4 d4 = *(const int4*)(dstp + e);
    int4 s4 = *(const int4*)(srcp + e);
    int dd[4] = {d4.x, d4.y, d4.z, d4.w};
    int ss[4] = {s4.x, s4.y, s4.z, s4.w};
#pragma unroll
    for (int j = 0; j < 4; ++j) {
      int pos = atomicAdd(&cur[dd[j] >> sh], 1);   // LDS atomic
      b[pos] = (u32)ss[j] | (((u32)dd[j] & fm) << 24);
    }
  }
}

__global__ __launch_bounds__(256) void csr_fine_k(
    const u32* __restrict__ bp, const int* __restrict__ hista,
    int* __restrict__ rowptrb, int* __restrict__ esrcb, CsrP cp) {
  const int hop = blockIdx.y, p = blockIdx.x;
  const int P = cp.P[hop];
  if (p >= P) return;
  const int n = cp.n[hop], sh = cp.sh[hop], W = 1 << sh;
  const int* fl = hista + (size_t)hop * HSTRIDE;
  const int beg = fl[p * NCH];
  const int end = (p + 1 < P) ? fl[(p + 1) * NCH] : E_EDGES;
  const int nb = min(W, n - p * W);
  const int tid = threadIdx.x;

  __shared__ int fh[256];
  __shared__ int sc[256];
  __shared__ int cur[256];
  fh[tid] = 0;
  __syncthreads();
  const u32* b = bp + (size_t)hop * E_EDGES;
  for (int i = beg + tid; i < end; i += 256)
    atomicAdd(&fh[b[i] >> 24], 1);
  __syncthreads();
  sc[tid] = fh[tid];
  __syncthreads();
  for (int off = 1; off < 256; off <<= 1) {
    int v = (tid >= off) ? sc[tid - off] : 0;
    __syncthreads();
    sc[tid] += v;
    __syncthreads();
  }
  const int excl = tid ? sc[tid - 1] : 0;
  int* rowptr = rowptrb + (size_t)hop * RP_STRIDE;
  if (tid < nb) rowptr[p * W + tid] = beg + excl;
  cur[tid] = beg + excl;
  if (p == P - 1 && tid == 0) rowptr[n] = E_EDGES;
  __syncthreads();
  int* esrc = esrcb + (size_t)hop * E_EDGES;
  for (int i = beg + tid; i < end; i += 256) {
    u32 v = b[i];
    int pos = atomicAdd(&cur[v >> 24], 1);        // LDS atomic
    esrc[pos] = (int)(v & 0xFFFFFFu);
  }
}

// ---------------------------------------------------------------------------
// Level-batched fused hop kernel v4: NO LDS — B-fragments read directly from
// global (Bt is 32KB, L1/L2-hot, shared by all blocks). No __syncthreads.
// 256 thr / 4 waves / 64 rows per block; 2-deep gather unroll.
struct HopJob {
  const u16* h; const int* rowptr; const int* esrc;
  const u16* Bt; const float* bias; u16* out;
  const int* iperm; int n; int permout;
};
struct HopBatch { HopJob j[6]; };

__global__ __launch_bounds__(256, 4) void hop_b_k(HopBatch batch) {
  const HopJob jb = batch.j[blockIdx.y];
  const int rbase = blockIdx.x * 64;
  if (rbase >= jb.n) return;

  const int tid = threadIdx.x;
  const int wave = tid >> 6;
  const int lane = tid & 63;
  const int kgrp = lane >> 4;
  const int lid  = lane & 15;
  const int d = rbase + wave * 16 + lid;

  float a0[8] = {0,0,0,0,0,0,0,0}, a1[8] = {0,0,0,0,0,0,0,0};
  float a2[8] = {0,0,0,0,0,0,0,0}, a3[8] = {0,0,0,0,0,0,0,0};
  int s0 = 0, s1 = 0;
  if (d < jb.n) { s0 = jb.rowptr[d]; s1 = jb.rowptr[d + 1]; }
  const u16* hk = jb.h + kgrp * 8;
  int i = s0;
  for (; i + 1 < s1; i += 2) {               // 2 edges x 4 segs = 8 loads in flight
    const u16* ra = hk + (size_t)jb.esrc[i] * 128;
    const u16* rb = hk + (size_t)jb.esrc[i + 1] * 128;
    uint4 va0 = *(const uint4*)(ra);      uint4 vb0 = *(const uint4*)(rb);
    uint4 va1 = *(const uint4*)(ra + 32); uint4 vb1 = *(const uint4*)(rb + 32);
    uint4 va2 = *(const uint4*)(ra + 64); uint4 vb2 = *(const uint4*)(rb + 64);
    uint4 va3 = *(const uint4*)(ra + 96); uint4 vb3 = *(const uint4*)(rb + 96);
    acc8(a0, va0); acc8(a1, va1); acc8(a2, va2); acc8(a3, va3);
    acc8(a0, vb0); acc8(a1, vb1); acc8(a2, vb2); acc8(a3, vb3);
  }
  if (i < s1) {
    const u16* ra = hk + (size_t)jb.esrc[i] * 128;
    acc8(a0, *(const uint4*)(ra));
    acc8(a1, *(const uint4*)(ra + 32));
    acc8(a2, *(const uint4*)(ra + 64));
    acc8(a3, *(const uint4*)(ra + 96));
  }
  const float rs = 1.0f / fmaxf((float)(s1 - s0), 1.0f);
  s8vec f0, f1, f2, f3;
#pragma unroll
  for (int j = 0; j < 8; ++j) f0[j] = (short)f2bf(a0[j] * rs);
#pragma unroll
  for (int j = 0; j < 8; ++j) f1[j] = (short)f2bf(a1[j] * rs);
#pragma unroll
  for (int j = 0; j < 8; ++j) f2[j] = (short)f2bf(a2[j] * rs);
#pragma unroll
  for (int j = 0; j < 8; ++j) f3[j] = (short)f2bf(a3[j] * rs);

  // output rows for this lane's C fragment
  int rout[4];
#pragma unroll
  for (int j = 0; j < 4; ++j) {
    int rv = rbase + wave * 16 + kgrp * 4 + j;
    rout[j] = (rv < jb.n) ? (jb.permout ? jb.iperm[rv] : rv) : -1;
  }

#pragma unroll
  for (int t = 0; t < 8; ++t) {
    f4vec c = {0.f, 0.f, 0.f, 0.f};
    const int bn = t * 16 + lid;
    const u16* brow = jb.Bt + (size_t)bn * 128;
    // B-frags straight from global: 16B/lane, L1/L2-hot (Bt = 32KB shared)
    c = __builtin_amdgcn_mfma_f32_16x16x32_bf16(f0, *(const s8vec*)(brow + kgrp * 8), c, 0, 0, 0);
    c = __builtin_amdgcn_mfma_f32_16x16x32_bf16(f1, *(const s8vec*)(brow + 32 + kgrp * 8), c, 0, 0, 0);
    c = __builtin_amdgcn_mfma_f32_16x16x32_bf16(f2, *(const s8vec*)(brow + 64 + kgrp * 8), c, 0, 0, 0);
    c = __builtin_amdgcn_mfma_f32_16x16x32_bf16(f3, *(const s8vec*)(brow + 96 + kgrp * 8), c, 0, 0, 0);
    const float bb = jb.bias[bn];
#pragma unroll
    for (int j = 0; j < 4; ++j) {
      if (rout[j] >= 0) {
        float v = c[j] + bb;
        jb.out[(size_t)rout[j] * 128 + bn] = f2bf(v);
      }
    }
  }
}

// ---------------------------------------------------------------------------
// Batched MFMA GEMM: C[M][N] = act(A[M][K] @ B[K][N] + bias); Bt=[N][K] bf16.
struct GemmJob {
  const void* A; const u16* Bt; const float* bias; void* C;
  const u16* target; float* loss; u16* Ct; int M;
};
struct GemmBatch { GemmJob j[3]; };

template <int K, int N, int ACT, int AMODE, bool CF32, bool SQDIFF, bool CTR>
__global__ __launch_bounds__(256) void gemm_b_k(
    GemmBatch batch, int ldA, int ldC, int ldCt) {
  static_assert(K % 32 == 0 && N % 16 == 0, "");
  const GemmJob jb = batch.j[blockIdx.y];
  const int rbase0 = blockIdx.x * 64;
  if (rbase0 >= jb.M) return;

  __shared__ u16 bts[N * K];
  __shared__ float red[4];

  const int tid = threadIdx.x;
  for (int i = tid; i < N * (K / 8); i += 256) {
    int n = i / (K / 8);
    int g = i % (K / 8);
    int gs = (g & ~7) | ((g ^ n) & 7);
    *(uint4*)(&bts[n * K + gs * 8]) = *(const uint4*)(jb.Bt + (size_t)n * K + g * 8);
  }
  __syncthreads();

  const int wave = tid >> 6;
  const int lane = tid & 63;
  const int kgrp = lane >> 4;
  const int rbase = rbase0 + wave * 16;
  const int rowA = rbase + (lane & 15);
  const bool av = rowA < jb.M;

  s8vec afr[K / 32];
  if constexpr (AMODE == 1) {
    const float* arow = (const float*)jb.A + (size_t)rowA * ldA;
#pragma unroll
    for (int kt = 0; kt < K / 32; ++kt) {
      s8vec fr = {0, 0, 0, 0, 0, 0, 0, 0};
      if (av) {
        const float* p = arow + kt * 32 + kgrp * 8;
        float4 fa = *(const float4*)(p);
        float4 fb = *(const float4*)(p + 4);
        fr[0] = (short)f2bf(fa.x); fr[1] = (short)f2bf(fa.y);
        fr[2] = (short)f2bf(fa.z); fr[3] = (short)f2bf(fa.w);
        fr[4] = (short)f2bf(fb.x); fr[5] = (short)f2bf(fb.y);
        fr[6] = (short)f2bf(fb.z); fr[7] = (short)f2bf(fb.w);
      }
      afr[kt] = fr;
    }
  } else {
    const u16* arow = (const u16*)jb.A + (size_t)rowA * ldA;
#pragma unroll
    for (int kt = 0; kt < K / 32; ++kt) {
      s8vec fr = {0, 0, 0, 0, 0, 0, 0, 0};
      if (av) fr = *(const s8vec*)(arow + kt * 32 + kgrp * 8);
      afr[kt] = fr;
    }
  }

  float sqsum = 0.0f;
#pragma unroll
  for (int t = 0; t < N / 16; ++t) {
    f4vec acc = {0.f, 0.f, 0.f, 0.f};
    const int bn = t * 16 + (lane & 15);
#pragma unroll
    for (int kt = 0; kt < K / 32; ++kt) {
      int g = kt * 4 + kgrp;
      int gs = (g & ~7) | ((g ^ bn) & 7);
      s8vec bfr = *(const s8vec*)(&bts[bn * K + gs * 8]);
      acc = __builtin_amdgcn_mfma_f32_16x16x32_bf16(afr[kt], bfr, acc, 0, 0, 0);
    }
    const int col = t * 16 + (lane & 15);
    float bb = jb.bias ? jb.bias[col] : 0.0f;
#pragma unroll
    for (int j = 0; j < 4; ++j) {
      int r = rbase + kgrp * 4 + j;        // C/D: col=lane&15, row=(lane>>4)*4+j
      if (r < jb.M) {
        float v = acc[j] + bb;
        if constexpr (ACT == ACT_RELU) v = fmaxf(v, 0.0f);
        if constexpr (ACT == ACT_TANH) v = tanhf(v);
        if constexpr (SQDIFF) {
          float dd = v - bf2f(jb.target[(size_t)r * N + col]);
          sqsum += dd * dd;
        } else if constexpr (CF32) {
          ((float*)jb.C)[(size_t)r * ldC + col] = v;
        } else {
          ((u16*)jb.C)[(size_t)r * ldC + col] = f2bf(v);
        }
        if constexpr (CTR) {
          jb.Ct[(size_t)col * ldCt + r] = f2bf(v);
        }
      }
    }
  }

  if constexpr (SQDIFF) {
#pragma unroll
    for (int off = 32; off > 0; off >>= 1) sqsum += __shfl_down(sqsum, off);
    if (lane == 0) red[wave] = sqsum;
    __syncthreads();
    if (tid == 0) atomicAdd(jb.loss, red[0] + red[1] + red[2] + red[3]);
  }
}

// ---------------------------------------------------------------------------
// Gram via MFMA: pair (p,q), G_pair[m][n] += sum_r ZT[p*64+m][r]*ZT[q*64+n][r]
#define GRAM_NKB 40
__global__ __launch_bounds__(256) void gram_k(
    const u16* __restrict__ zt, int NP, float* __restrict__ G3) {
  const int pair = blockIdx.y;
  const int p = (pair == 2) ? 1 : 0;
  const int q = (pair == 0) ? 1 : 2;
  const int wave = threadIdx.x >> 6;
  const int lane = threadIdx.x & 63;
  const int kgrp = lane >> 4, lid = lane & 15;

  const int KC = (((NP + GRAM_NKB - 1) / GRAM_NKB) + 31) & ~31;
  const int kbeg = blockIdx.x * KC;
  const int kend = min(NP, kbeg + KC);

  const u16* arow = zt + (size_t)(p * 64 + wave * 16 + lid) * NP;
  const u16* brow0 = zt + (size_t)(q * 64 + 0 * 16 + lid) * NP;
  const u16* brow1 = zt + (size_t)(q * 64 + 1 * 16 + lid) * NP;
  const u16* brow2 = zt + (size_t)(q * 64 + 2 * 16 + lid) * NP;
  const u16* brow3 = zt + (size_t)(q * 64 + 3 * 16 + lid) * NP;

  f4vec acc0 = {0.f, 0.f, 0.f, 0.f};
  f4vec acc1 = {0.f, 0.f, 0.f, 0.f};
  f4vec acc2 = {0.f, 0.f, 0.f, 0.f};
  f4vec acc3 = {0.f, 0.f, 0.f, 0.f};

  for (int k0 = kbeg; k0 < kend; k0 += 32) {
    const int ko = k0 + kgrp * 8;
    s8vec af = *(const s8vec*)(arow + ko);
    s8vec b0 = *(const s8vec*)(brow0 + ko);
    s8vec b1 = *(const s8vec*)(brow1 + ko);
    s8vec b2 = *(const s8vec*)(brow2 + ko);
    s8vec b3 = *(const s8vec*)(brow3 + ko);
    acc0 = __builtin_amdgcn_mfma_f32_16x16x32_bf16(af, b0, acc0, 0, 0, 0);
    acc1 = __builtin_amdgcn_mfma_f32_16x16x32_bf16(af, b1, acc1, 0, 0, 0);
    acc2 = __builtin_amdgcn_mfma_f32_16x16x32_bf16(af, b2, acc2, 0, 0, 0);
    acc3 = __builtin_amdgcn_mfma_f32_16x16x32_bf16(af, b3, acc3, 0, 0, 0);
  }

  float* g = G3 + (size_t)pair * 4096;
  const int mrow = wave * 16 + kgrp * 4;
#pragma unroll
  for (int j = 0; j < 4; ++j) {
    atomicAdd(&g[(mrow + j) * 64 + 0 * 16 + lid], acc0[j]);
    atomicAdd(&g[(mrow + j) * 64 + 1 * 16 + lid], acc1[j]);
    atomicAdd(&g[(mrow + j) * 64 + 2 * 16 + lid], acc2[j]);
    atomicAdd(&g[(mrow + j) * 64 + 3 * 16 + lid], acc3[j]);
  }
}

// ---------------------------------------------------------------------------
__global__ __launch_bounds__(256) void loss_k(
    const float* __restrict__ G, const float* __restrict__ RE,
    float* __restrict__ out) {
  float s = 0.f;
  for (int i = threadIdx.x; i < 2 * 3 * 4096; i += 256) { float g = G[i]; s += g * g; }
#pragma unroll
  for (int off = 32; off > 0; off >>= 1) s += __shfl_down(s, off);
  __shared__ float red[4];
  int wave = threadIdx.x >> 6, lane = threadIdx.x & 63;
  if (lane == 0) red[wave] = s;
  __syncthreads();
  if (threadIdx.x == 0) {
    float orth = (red[0] + red[1] + red[2] + red[3]) / 4096.0f;
    float loss = orth + RE[0] / (50000.0f * 128.0f) + RE[1] / (80000.0f * 128.0f);
    out[0] = loss;
  }
}

// ---------------------------------------------------------------------------
static const int COUNTS_H[3] = {50000, 80000, 10000};
static const int OFFS_H[3]   = {0, 50000, 130000};
static const int GRP_H[5]    = {2, 1, 1, 2, 1};                // GCN_GROUP
static const int HOPN[14] = {80000, 50000, 80000, 10000, 80000, 50000, 50000,
                             50000, 80000, 10000, 80000, 50000, 50000, 80000};

extern "C" void kernel_launch(void* const* d_in, const int* in_sizes, int n_in,
                              void* d_out, int out_size, void* d_ws, size_t ws_size,
                              hipStream_t stream) {
  (void)in_sizes; (void)n_in; (void)out_size; (void)ws_size;

  const float* features = (const float*)d_in[0];
  const int* e_user   = (const int*)d_in[1];
  const int* e_item   = (const int*)d_in[2];
  const int* perm_u   = (const int*)d_in[3];
  const int* perm_i   = (const int*)d_in[4];
  const float* W_type = (const float*)d_in[5];
  const float* b_type = (const float*)d_in[6];
  const float* comp   = (const float*)d_in[7];
  const float* W_gcn  = (const float*)d_in[8];
  const float* b_gcn  = (const float*)d_in[9];
  const float* fc[2]  = {(const float*)d_in[10], (const float*)d_in[14]};
  const float* fcr[2] = {(const float*)d_in[11], (const float*)d_in[15]};
  const float* V[2]   = {(const float*)d_in[12], (const float*)d_in[16]};
  const float* Vr[2]  = {(const float*)d_in[13], (const float*)d_in[17]};
  float* out = (float*)d_out;

  char* base = (char*)d_ws;
  size_t off = 0;
  auto alloc = [&](size_t b) -> void* {
    void* p = base + off;
    off = (off + b + 255) & ~(size_t)255;
    return p;
  };
  u16* TF    = (u16*)alloc(140000ull * 128 * 2);
  u16* HB    = (u16*)alloc(330000ull * 128 * 2);   // 7 chain buffers; aliased as BP early
  u16* OUTSu = (u16*)alloc(3ull * 50000 * 128 * 2);
  u16* OUTSi = (u16*)alloc(3ull * 80000 * 128 * 2);
  int* HISTA    = (int*)alloc(14ull * HSTRIDE * 4);   // ZT aliases from here
  int* ROWPTR14 = (int*)alloc(14ull * RP_STRIDE * 4);
  int* ESRC14   = (int*)alloc(14ull * E_EDGES * 4);
  int* IPERM    = (int*)alloc(130000ull * 4);         // [user 50k][item 80k]
  u16* WT_TYPE = (u16*)alloc(3ull * 128 * 256 * 2);
  u16* BT_HOP  = (u16*)alloc(5ull * 128 * 128 * 2);
  u16* FCT     = (u16*)alloc(6ull * 64 * 128 * 2);
  u16* VT      = (u16*)alloc(2ull * 128 * 192 * 2);
  u16* VRT     = (u16*)alloc(2ull * 192 * 128 * 2);
  u16* FCRT    = (u16*)alloc(6ull * 128 * 64 * 2);
  float* G   = (float*)alloc((2 * 3 * 4096 + 2) * 4);
  float* RE  = G + 2 * 3 * 4096;

  // aliases (lifetimes disjoint):
  u32* BP   = (u32*)HB;            // 28 MB <= 84.5 MB; dead before hop L0
  u16* Z    = HB;                  // fusion phase; HB dead after hops
  u16* ZREC = HB + 80000ull * 192;
  u16* ZT   = (u16*)HISTA;         // 30.73 MB <= HISTA+ROWPTR+ESRC (33.6 MB); CSR dead after hops

  const int hbrow[7] = {0, 80000, 160000, 170000, 220000, 230000, 280000};
  auto HBp = [&](int c) { return HB + (size_t)hbrow[c] * 128; };
  auto RP  = [&](int g) { return ROWPTR14 + (size_t)g * RP_STRIDE; };
  auto ES  = [&](int g) { return ESRC14 + (size_t)g * E_EDGES; };
  auto BT  = [&](int et) { return BT_HOP + (size_t)et * 128 * 128; };
  auto BG  = [&](int et) { return b_gcn + (size_t)GRP_H[et] * 128; };

  // ---- batched weight transposes (24 jobs) --------------------------------
  TBatch tb;
  int tj = 0;
  for (int t = 0; t < 3; ++t)
    tb.j[tj++] = {W_type + (size_t)t * 256 * 128, WT_TYPE + (size_t)t * 128 * 256, nullptr, 256, 128};
  for (int et = 0; et < 5; ++et)
    tb.j[tj++] = {W_gcn + (size_t)GRP_H[et] * 128 * 128, BT_HOP + (size_t)et * 128 * 128,
                  comp + (size_t)et * 128, 128, 128};
  for (int L = 0; L < 2; ++L)
    for (int p = 0; p < 3; ++p)
      tb.j[tj++] = {fc[L] + (size_t)p * 128 * 64, FCT + (size_t)(L * 3 + p) * 64 * 128, nullptr, 128, 64};
  for (int L = 0; L < 2; ++L)
    for (int p = 0; p < 3; ++p)
      tb.j[tj++] = {fcr[L] + (size_t)p * 64 * 128, FCRT + (size_t)(L * 3 + p) * 128 * 64, nullptr, 64, 128};
  for (int L = 0; L < 2; ++L)
    tb.j[tj++] = {V[L], VT + (size_t)L * 128 * 192, nullptr, 192, 128};
  for (int L = 0; L < 2; ++L)
    tb.j[tj++] = {Vr[L], VRT + (size_t)L * 192 * 128, nullptr, 128, 192};
  transpose_b_k<<<dim3(128, 24), 256, 0, stream>>>(tb);

  // ---- inverse perms -------------------------------------------------------
  IBatch ib;
  ib.perm[0] = perm_u; ib.ip[0] = IPERM;          ib.n[0] = 50000;
  ib.perm[1] = perm_i; ib.ip[1] = IPERM + 50000;  ib.n[1] = 80000;
  iperm_b_k<<<dim3(313, 2), 256, 0, stream>>>(ib);

  // ---- CSR build for all 14 hops (two-level bucket sort, no global atomics)
  CsrP cpp;
  for (int g = 0; g < 14; ++g) {
    cpp.n[g] = HOPN[g];
    cpp.sh[g] = (HOPN[g] <= 10000) ? 6 : 8;
    cpp.P[g] = (HOPN[g] + (1 << cpp.sh[g]) - 1) >> cpp.sh[g];
  }
  csr_hist_k<<<dim3(NCH, 14), 256, 0, stream>>>(e_user, e_item, HISTA, cpp);
  csr_scan_k<<<dim3(14), 256, 0, stream>>>(HISTA, cpp);
  csr_scatter_k<<<dim3(NCH, 14), 256, 0, stream>>>(e_user, e_item, HISTA, BP, cpp);
  csr_fine_k<<<dim3(313, 14), 256, 0, stream>>>(BP, HISTA, ROWPTR14, ESRC14, cpp);
  hipMemsetAsync(G, 0, (2 * 3 * 4096 + 2) * 4, stream);

  // ---- NodeTransform (batched, 3 types) -----------------------------------
  {
    GemmBatch nb;
    for (int t = 0; t < 3; ++t)
      nb.j[t] = {features + (size_t)OFFS_H[t] * 256, WT_TYPE + (size_t)t * 128 * 256,
                 b_type + (size_t)t * 128, TF + (size_t)OFFS_H[t] * 128,
                 nullptr, nullptr, nullptr, COUNTS_H[t]};
    gemm_b_k<256, 128, ACT_RELU, 1, false, false, false>
        <<<dim3(1250, 3), 256, 0, stream>>>(nb, 256, 128, 0);
  }

  // ---- hops in 4 dependency levels ----------------------------------------
  const u16* TF0 = TF;
  const u16* TF1 = TF + 50000ull * 128;
  const int* IPu = IPERM;
  const int* IPi = IPERM + 50000;

  HopBatch L0, L1, L2, L3;
  L0.j[0] = {TF0, RP(0),  ES(0),  BT(0), BG(0), HBp(0), nullptr, 80000, 0};
  L0.j[1] = {TF0, RP(2),  ES(2),  BT(0), BG(0), HBp(1), nullptr, 80000, 0};
  L0.j[2] = {TF0, RP(6),  ES(6),  BT(4), BG(4), OUTSu + 2ull * 50000 * 128, IPu, 50000, 1};
  L0.j[3] = {TF1, RP(7),  ES(7),  BT(1), BG(1), HBp(3), nullptr, 50000, 0};
  L0.j[4] = {TF1, RP(9),  ES(9),  BT(2), BG(2), HBp(4), nullptr, 10000, 0};
  L0.j[5] = {TF1, RP(11), ES(11), BT(1), BG(1), HBp(5), nullptr, 50000, 0};
  L1.j[0] = {HBp(0), RP(1),  ES(1),  BT(1), BG(1), OUTSu, IPu, 50000, 1};
  L1.j[1] = {HBp(1), RP(3),  ES(3),  BT(2), BG(2), HBp(2), nullptr, 10000, 0};
  L1.j[2] = {HBp(3), RP(8),  ES(8),  BT(0), BG(0), OUTSi, IPi, 80000, 1};
  L1.j[3] = {HBp(4), RP(10), ES(10), BT(3), BG(3), OUTSi + 1ull * 80000 * 128, IPi, 80000, 1};
  L1.j[4] = {HBp(5), RP(12), ES(12), BT(4), BG(4), HBp(6), nullptr, 50000, 0};
  L1.j[5] = L1.j[4];
  L2.j[0] = {HBp(2), RP(4),  ES(4),  BT(3), BG(3), HBp(0), nullptr, 80000, 0};
  L2.j[1] = {HBp(6), RP(13), ES(13), BT(0), BG(0), OUTSi + 2ull * 80000 * 128, IPi, 80000, 1};
  L2.j[2] = L2.j[1]; L2.j[3] = L2.j[1]; L2.j[4] = L2.j[1]; L2.j[5] = L2.j[1];
  L3.j[0] = {HBp(0), RP(5), ES(5), BT(1), BG(1), OUTSu + 1ull * 50000 * 128, IPu, 50000, 1};
  L3.j[1] = L3.j[0]; L3.j[2] = L3.j[0]; L3.j[3] = L3.j[0]; L3.j[4] = L3.j[0]; L3.j[5] = L3.j[0];

  hop_b_k<<<dim3(1250, 6), 256, 0, stream>>>(L0);
  hop_b_k<<<dim3(1250, 5), 256, 0, stream>>>(L1);
  hop_b_k<<<dim3(1250, 2), 256, 0, stream>>>(L2);
  hop_b_k<<<dim3(782, 1), 256, 0, stream>>>(L3);

  // ---- fusion per layer ----------------------------------------------------
  for (int L = 0; L < 2; ++L) {
    const int nL = L ? 80000 : 50000;
    const int NP = (nL + 31) & ~31;
    u16* OUTS_L = L ? OUTSi : OUTSu;
    const size_t pstride = (size_t)nL * 128;
    const dim3 gg((unsigned)((nL + 63) / 64));

    if (NP != nL)
      hipMemsetAsync(ZT, 0, (size_t)192 * NP * 2, stream);

    GemmBatch fb;
    for (int p = 0; p < 3; ++p)
      fb.j[p] = {OUTS_L + p * pstride, FCT + (size_t)(L * 3 + p) * 64 * 128, nullptr,
                 Z + p * 64, nullptr, nullptr, ZT + (size_t)p * 64 * NP, nL};
    gemm_b_k<128, 64, ACT_TANH, 0, false, false, true>
        <<<dim3(gg.x, 3), 256, 0, stream>>>(fb, 128, 192, NP);

    gram_k<<<dim3(GRAM_NKB, 3), 256, 0, stream>>>(ZT, NP, G + (size_t)L * 3 * 4096);

    float* fused = out + (L ? 6400000 : 0);
    GemmBatch vb;
    vb.j[0] = {Z, VT + (size_t)L * 128 * 192, nullptr, fused, nullptr, nullptr, nullptr, nL};
    vb.j[1] = vb.j[0]; vb.j[2] = vb.j[0];
    gemm_b_k<192, 128, ACT_NONE, 0, true, false, false>
        <<<dim3(gg.x, 1), 256, 0, stream>>>(vb, 192, 128, 0);

    GemmBatch rb;
    rb.j[0] = {fused, VRT + (size_t)L * 192 * 128, nullptr, ZREC, nullptr, nullptr, nullptr, nL};
    rb.j[1] = rb.j[0]; rb.j[2] = rb.j[0];
    gemm_b_k<128, 192, ACT_NONE, 1, false, false, false>
        <<<dim3(gg.x, 1), 256, 0, stream>>>(rb, 128, 192, 0);

    GemmBatch sb;
    for (int p = 0; p < 3; ++p)
      sb.j[p] = {ZREC + p * 64, FCRT + (size_t)(L * 3 + p) * 128 * 64, nullptr,
                 nullptr, OUTS_L + p * pstride, RE + L, nullptr, nL};
    gemm_b_k<64, 128, ACT_NONE, 0, false, true, false>
        <<<dim3(gg.x, 3), 256, 0, stream>>>(sb, 192, 0, 0);
  }

  loss_k<<<1, 256, 0, stream>>>(G, RE, out + 16640000);
}

// Round 14
// 1042.997 us; speedup vs baseline: 1.1134x; 1.1134x over previous
//
#include <hip/hip_runtime.h>

typedef unsigned short u16;
typedef unsigned int   u32;

#define ACT_NONE 0
#define ACT_RELU 1
#define ACT_TANH 2

#define E_EDGES 500000
#define RP_STRIDE 80004   // per-hop stride for rowptr (ints, 16B-aligned)
#define NCH 62            // edge chunks per hop (8192 edges each)
#define CH 8192
#define HSTRIDE 19456     // per-hop stride in HISTA (>= maxP(313)*NCH(62)=19406)

using s8vec = __attribute__((ext_vector_type(8))) short;   // 8 bf16 (4 VGPRs) MFMA A/B frag
using f4vec = __attribute__((ext_vector_type(4))) float;   // MFMA C/D frag

__device__ __forceinline__ float bf2f(u16 u) {
  union { u32 b; float f; } v; v.b = ((u32)u) << 16; return v.f;
}
__device__ __forceinline__ u16 f2bf(float x) {
  union { float f; u32 b; } v; v.f = x;
  u32 r = v.b + 0x7fffu + ((v.b >> 16) & 1u);   // round-to-nearest-even
  return (u16)(r >> 16);
}
__device__ __forceinline__ void acc8(float* acc, uint4 v) {
  union { u32 b; float f; } cv;
  cv.b = v.x << 16;         acc[0] += cv.f;
  cv.b = v.x & 0xffff0000u; acc[1] += cv.f;
  cv.b = v.y << 16;         acc[2] += cv.f;
  cv.b = v.y & 0xffff0000u; acc[3] += cv.f;
  cv.b = v.z << 16;         acc[4] += cv.f;
  cv.b = v.z & 0xffff0000u; acc[5] += cv.f;
  cv.b = v.w << 16;         acc[6] += cv.f;
  cv.b = v.w & 0xffff0000u; acc[7] += cv.f;
}

// ---------------------------------------------------------------------------
// batched transpose + cast f32->bf16 (+ optional per-row scale): in[R][C]->out[C][R]
struct TJob { const float* src; u16* dst; const float* scale; int R; int C; };
struct TBatch { TJob j[24]; };
__global__ __launch_bounds__(256) void transpose_b_k(TBatch b) {
  TJob jb = b.j[blockIdx.y];
  int i = blockIdx.x * 256 + threadIdx.x;
  if (i >= jb.R * jb.C) return;
  int r = i / jb.C, c = i % jb.C;
  float v = jb.src[i];
  if (jb.scale) v *= jb.scale[r];
  jb.dst[(size_t)c * jb.R + r] = f2bf(v);
}

// ---------------------------------------------------------------------------
// batched inverse permutation: ip[perm[i]] = i
struct IBatch { const int* perm[2]; int* ip[2]; int n[2]; };
__global__ __launch_bounds__(256) void iperm_b_k(IBatch b) {
  int y = blockIdx.y;
  int i = blockIdx.x * 256 + threadIdx.x;
  if (i < b.n[y]) b.ip[y][b.perm[y][i]] = i;
}

// ---------------------------------------------------------------------------
// Two-level bucket CSR build over 14 hops — ZERO global atomics.
struct CsrP { int n[14]; int sh[14]; int P[14]; };

__global__ __launch_bounds__(256) void csr_hist_k(
    const int* __restrict__ eu, const int* __restrict__ ei,
    int* __restrict__ hista, CsrP cp) {
  const int hop = blockIdx.y, chunk = blockIdx.x;
  const int P = cp.P[hop], sh = cp.sh[hop];
  __shared__ int hist[320];
  for (int i = threadIdx.x; i < P; i += 256) hist[i] = 0;
  __syncthreads();
  const int* edges = (hop < 7) ? eu : ei;
  const int h7 = (hop < 7) ? hop : hop - 7;
  const int* dstp = edges + (size_t)(h7 * 2 + 1) * E_EDGES;
  const int e0 = chunk * CH;
  const int e1 = min(E_EDGES, e0 + CH);
  for (int e = e0 + threadIdx.x * 4; e < e1; e += 1024) {
    int4 d4 = *(const int4*)(dstp + e);
    atomicAdd(&hist[d4.x >> sh], 1);
    atomicAdd(&hist[d4.y >> sh], 1);
    atomicAdd(&hist[d4.z >> sh], 1);
    atomicAdd(&hist[d4.w >> sh], 1);
  }
  __syncthreads();
  for (int i = threadIdx.x; i < P; i += 256)
    hista[(size_t)hop * HSTRIDE + i * NCH + chunk] = hist[i];
}

__global__ __launch_bounds__(256) void csr_scan_k(int* __restrict__ hista, CsrP cp) {
  const int hop = blockIdx.x;
  const int L = cp.P[hop] * NCH;
  int* a = hista + (size_t)hop * HSTRIDE;
  const int per = (L + 255) >> 8;
  const int lo = threadIdx.x * per;
  const int hi = min(L, lo + per);
  int s = 0;
  for (int i = lo; i < hi; ++i) s += a[i];
  __shared__ int lds[256];
  lds[threadIdx.x] = s;
  __syncthreads();
  for (int off = 1; off < 256; off <<= 1) {
    int v = (threadIdx.x >= off) ? lds[threadIdx.x - off] : 0;
    __syncthreads();
    lds[threadIdx.x] += v;
    __syncthreads();
  }
  int run = threadIdx.x ? lds[threadIdx.x - 1] : 0;
  for (int i = lo; i < hi; ++i) { int v = a[i]; a[i] = run; run += v; }
}

__global__ __launch_bounds__(256) void csr_scatter_k(
    const int* __restrict__ eu, const int* __restrict__ ei,
    const int* __restrict__ hista, u32* __restrict__ bp, CsrP cp) {
  const int hop = blockIdx.y, chunk = blockIdx.x;
  const int P = cp.P[hop], sh = cp.sh[hop];
  const u32 fm = (1u << sh) - 1u;
  __shared__ int cur[320];
  for (int i = threadIdx.x; i < P; i += 256)
    cur[i] = hista[(size_t)hop * HSTRIDE + i * NCH + chunk];
  __syncthreads();
  const int* edges = (hop < 7) ? eu : ei;
  const int h7 = (hop < 7) ? hop : hop - 7;
  const int* srcp = edges + (size_t)(h7 * 2) * E_EDGES;
  const int* dstp = srcp + E_EDGES;
  u32* b = bp + (size_t)hop * E_EDGES;
  const int e0 = chunk * CH;
  const int e1 = min(E_EDGES, e0 + CH);
  for (int e = e0 + threadIdx.x * 4; e < e1; e += 1024) {
    int4 d4 = *(const int4*)(dstp + e);
    int4 s4 = *(const int4*)(srcp + e);
    int dd[4] = {d4.x, d4.y, d4.z, d4.w};
    int ss[4] = {s4.x, s4.y, s4.z, s4.w};
#pragma unroll
    for (int j = 0; j < 4; ++j) {
      int pos = atomicAdd(&cur[dd[j] >> sh], 1);   // LDS atomic
      b[pos] = (u32)ss[j] | (((u32)dd[j] & fm) << 24);
    }
  }
}

__global__ __launch_bounds__(256) void csr_fine_k(
    const u32* __restrict__ bp, const int* __restrict__ hista,
    int* __restrict__ rowptrb, int* __restrict__ esrcb, CsrP cp) {
  const int hop = blockIdx.y, p = blockIdx.x;
  const int P = cp.P[hop];
  if (p >= P) return;
  const int n = cp.n[hop], sh = cp.sh[hop], W = 1 << sh;
  const int* fl = hista + (size_t)hop * HSTRIDE;
  const int beg = fl[p * NCH];
  const int end = (p + 1 < P) ? fl[(p + 1) * NCH] : E_EDGES;
  const int nb = min(W, n - p * W);
  const int tid = threadIdx.x;

  __shared__ int fh[256];
  __shared__ int sc[256];
  __shared__ int cur[256];
  fh[tid] = 0;
  __syncthreads();
  const u32* b = bp + (size_t)hop * E_EDGES;
  for (int i = beg + tid; i < end; i += 256)
    atomicAdd(&fh[b[i] >> 24], 1);
  __syncthreads();
  sc[tid] = fh[tid];
  __syncthreads();
  for (int off = 1; off < 256; off <<= 1) {
    int v = (tid >= off) ? sc[tid - off] : 0;
    __syncthreads();
    sc[tid] += v;
    __syncthreads();
  }
  const int excl = tid ? sc[tid - 1] : 0;
  int* rowptr = rowptrb + (size_t)hop * RP_STRIDE;
  if (tid < nb) rowptr[p * W + tid] = beg + excl;
  cur[tid] = beg + excl;
  if (p == P - 1 && tid == 0) rowptr[n] = E_EDGES;
  __syncthreads();
  int* esrc = esrcb + (size_t)hop * E_EDGES;
  for (int i = beg + tid; i < end; i += 256) {
    u32 v = b[i];
    int pos = atomicAdd(&cur[v >> 24], 1);        // LDS atomic
    esrc[pos] = (int)(v & 0xFFFFFFu);
  }
}

// ---------------------------------------------------------------------------
// Level-batched fused hop kernel (R10 config: LDS B-tile, 2-deep gather)
struct HopJob {
  const u16* h; const int* rowptr; const int* esrc;
  const u16* Bt; const float* bias; u16* out;
  const int* iperm; int n; int permout;
};
struct HopBatch { HopJob j[6]; };

__global__ __launch_bounds__(256) void hop_b_k(HopBatch batch) {
  const HopJob jb = batch.j[blockIdx.y];
  const int rbase = blockIdx.x * 64;
  if (rbase >= jb.n) return;

  __shared__ u16 bts[128 * 128];
  const int tid = threadIdx.x;
  // stage Bt[128][128] -> LDS with 16B-granule XOR swizzle
  for (int i = tid; i < 128 * 16; i += 256) {
    int nn = i >> 4, g = i & 15;
    int gs = (g & 8) | ((g ^ nn) & 7);
    *(uint4*)(&bts[nn * 128 + gs * 8]) = *(const uint4*)(jb.Bt + (size_t)nn * 128 + g * 8);
  }
  __syncthreads();

  const int wave = tid >> 6;
  const int lane = tid & 63;
  const int kgrp = lane >> 4;
  const int lid  = lane & 15;
  const int d = rbase + wave * 16 + lid;

  float a0[8] = {0,0,0,0,0,0,0,0}, a1[8] = {0,0,0,0,0,0,0,0};
  float a2[8] = {0,0,0,0,0,0,0,0}, a3[8] = {0,0,0,0,0,0,0,0};
  int s0 = 0, s1 = 0;
  if (d < jb.n) { s0 = jb.rowptr[d]; s1 = jb.rowptr[d + 1]; }
  const u16* hk = jb.h + kgrp * 8;
  int i = s0;
  for (; i + 1 < s1; i += 2) {
    const u16* ra = hk + (size_t)jb.esrc[i] * 128;
    const u16* rb = hk + (size_t)jb.esrc[i + 1] * 128;
    uint4 va0 = *(const uint4*)(ra);      uint4 vb0 = *(const uint4*)(rb);
    uint4 va1 = *(const uint4*)(ra + 32); uint4 vb1 = *(const uint4*)(rb + 32);
    uint4 va2 = *(const uint4*)(ra + 64); uint4 vb2 = *(const uint4*)(rb + 64);
    uint4 va3 = *(const uint4*)(ra + 96); uint4 vb3 = *(const uint4*)(rb + 96);
    acc8(a0, va0); acc8(a1, va1); acc8(a2, va2); acc8(a3, va3);
    acc8(a0, vb0); acc8(a1, vb1); acc8(a2, vb2); acc8(a3, vb3);
  }
  if (i < s1) {
    const u16* ra = hk + (size_t)jb.esrc[i] * 128;
    acc8(a0, *(const uint4*)(ra));
    acc8(a1, *(const uint4*)(ra + 32));
    acc8(a2, *(const uint4*)(ra + 64));
    acc8(a3, *(const uint4*)(ra + 96));
  }
  const float rs = 1.0f / fmaxf((float)(s1 - s0), 1.0f);
  s8vec f0, f1, f2, f3;
#pragma unroll
  for (int j = 0; j < 8; ++j) f0[j] = (short)f2bf(a0[j] * rs);
#pragma unroll
  for (int j = 0; j < 8; ++j) f1[j] = (short)f2bf(a1[j] * rs);
#pragma unroll
  for (int j = 0; j < 8; ++j) f2[j] = (short)f2bf(a2[j] * rs);
#pragma unroll
  for (int j = 0; j < 8; ++j) f3[j] = (short)f2bf(a3[j] * rs);

  int rout[4];
#pragma unroll
  for (int j = 0; j < 4; ++j) {
    int rv = rbase + wave * 16 + kgrp * 4 + j;
    rout[j] = (rv < jb.n) ? (jb.permout ? jb.iperm[rv] : rv) : -1;
  }

#pragma unroll
  for (int t = 0; t < 8; ++t) {
    f4vec c = {0.f, 0.f, 0.f, 0.f};
    const int bn = t * 16 + lid;
    int g = kgrp;
    int gs = (g & 8) | ((g ^ bn) & 7);
    c = __builtin_amdgcn_mfma_f32_16x16x32_bf16(f0, *(const s8vec*)(&bts[bn * 128 + gs * 8]), c, 0, 0, 0);
    g = 4 + kgrp; gs = (g & 8) | ((g ^ bn) & 7);
    c = __builtin_amdgcn_mfma_f32_16x16x32_bf16(f1, *(const s8vec*)(&bts[bn * 128 + gs * 8]), c, 0, 0, 0);
    g = 8 + kgrp; gs = (g & 8) | ((g ^ bn) & 7);
    c = __builtin_amdgcn_mfma_f32_16x16x32_bf16(f2, *(const s8vec*)(&bts[bn * 128 + gs * 8]), c, 0, 0, 0);
    g = 12 + kgrp; gs = (g & 8) | ((g ^ bn) & 7);
    c = __builtin_amdgcn_mfma_f32_16x16x32_bf16(f3, *(const s8vec*)(&bts[bn * 128 + gs * 8]), c, 0, 0, 0);
    const float bb = jb.bias[bn];
#pragma unroll
    for (int j = 0; j < 4; ++j) {
      if (rout[j] >= 0) {
        float v = c[j] + bb;
        jb.out[(size_t)rout[j] * 128 + bn] = f2bf(v);
      }
    }
  }
}

// ---------------------------------------------------------------------------
// Batched MFMA GEMM: C[M][N] = act(A[M][K] @ B[K][N] + bias); Bt=[N][K] bf16.
struct GemmJob {
  const void* A; const u16* Bt; const float* bias; void* C;
  u16* Ct; int M; int ldCt;
};
struct GemmBatch { GemmJob j[6]; };

template <int K, int N, int ACT, int AMODE, bool CF32, bool CTR>
__global__ __launch_bounds__(256) void gemm_b_k(
    GemmBatch batch, int ldA, int ldC) {
  static_assert(K % 32 == 0 && N % 16 == 0, "");
  const GemmJob jb = batch.j[blockIdx.y];
  const int rbase0 = blockIdx.x * 64;
  if (rbase0 >= jb.M) return;

  __shared__ u16 bts[N * K];

  const int tid = threadIdx.x;
  for (int i = tid; i < N * (K / 8); i += 256) {
    int n = i / (K / 8);
    int g = i % (K / 8);
    int gs = (g & ~7) | ((g ^ n) & 7);
    *(uint4*)(&bts[n * K + gs * 8]) = *(const uint4*)(jb.Bt + (size_t)n * K + g * 8);
  }
  __syncthreads();

  const int wave = tid >> 6;
  const int lane = tid & 63;
  const int kgrp = lane >> 4;
  const int rbase = rbase0 + wave * 16;
  const int rowA = rbase + (lane & 15);
  const bool av = rowA < jb.M;

  s8vec afr[K / 32];
  if constexpr (AMODE == 1) {
    const float* arow = (const float*)jb.A + (size_t)rowA * ldA;
#pragma unroll
    for (int kt = 0; kt < K / 32; ++kt) {
      s8vec fr = {0, 0, 0, 0, 0, 0, 0, 0};
      if (av) {
        const float* p = arow + kt * 32 + kgrp * 8;
        float4 fa = *(const float4*)(p);
        float4 fb = *(const float4*)(p + 4);
        fr[0] = (short)f2bf(fa.x); fr[1] = (short)f2bf(fa.y);
        fr[2] = (short)f2bf(fa.z); fr[3] = (short)f2bf(fa.w);
        fr[4] = (short)f2bf(fb.x); fr[5] = (short)f2bf(fb.y);
        fr[6] = (short)f2bf(fb.z); fr[7] = (short)f2bf(fb.w);
      }
      afr[kt] = fr;
    }
  } else {
    const u16* arow = (const u16*)jb.A + (size_t)rowA * ldA;
#pragma unroll
    for (int kt = 0; kt < K / 32; ++kt) {
      s8vec fr = {0, 0, 0, 0, 0, 0, 0, 0};
      if (av) fr = *(const s8vec*)(arow + kt * 32 + kgrp * 8);
      afr[kt] = fr;
    }
  }

#pragma unroll
  for (int t = 0; t < N / 16; ++t) {
    f4vec acc = {0.f, 0.f, 0.f, 0.f};
    const int bn = t * 16 + (lane & 15);
#pragma unroll
    for (int kt = 0; kt < K / 32; ++kt) {
      int g = kt * 4 + kgrp;
      int gs = (g & ~7) | ((g ^ bn) & 7);
      s8vec bfr = *(const s8vec*)(&bts[bn * K + gs * 8]);
      acc = __builtin_amdgcn_mfma_f32_16x16x32_bf16(afr[kt], bfr, acc, 0, 0, 0);
    }
    const int col = t * 16 + (lane & 15);
    float bb = jb.bias ? jb.bias[col] : 0.0f;
#pragma unroll
    for (int j = 0; j < 4; ++j) {
      int r = rbase + kgrp * 4 + j;        // C/D: col=lane&15, row=(lane>>4)*4+j
      if (r < jb.M) {
        float v = acc[j] + bb;
        if constexpr (ACT == ACT_RELU) v = fmaxf(v, 0.0f);
        if constexpr (ACT == ACT_TANH) v = tanhf(v);
        if constexpr (CF32) {
          ((float*)jb.C)[(size_t)r * ldC + col] = v;
        } else {
          ((u16*)jb.C)[(size_t)r * ldC + col] = f2bf(v);
        }
        if constexpr (CTR) {
          jb.Ct[(size_t)col * jb.ldCt + r] = f2bf(v);
        }
      }
    }
  }
}

// ---------------------------------------------------------------------------
// Fused V -> Vr -> fcr+sqdiff (3-stage, per layer): reads Z, writes fused (f32
// output), keeps fused & zrec tiles in swizzled LDS, accumulates recon loss.
struct VFJob {
  const u16* Z;      // [M][192]
  const u16* VT;     // [128][192]  (Bt stage1)
  const u16* VRT;    // [192][128]  (Bt stage2)
  const u16* FCRT;   // 3 x [128][64] (Bt stage3)
  const u16* target; // OUTS_L: 3 x [M][128]
  float* fused;      // [M][128] f32 (model output)
  float* loss;       // RE + L
  int M;
};

__global__ __launch_bounds__(256) void vfuse_k(VFJob j0, VFJob j1) {
  const VFJob jb = blockIdx.y ? j1 : j0;
  const int rbase = blockIdx.x * 64;
  if (rbase >= jb.M) return;

  __shared__ u16 ftile[64 * 128];   // fused tile, bf16, granule-swizzled
  __shared__ u16 ztile[64 * 192];   // zrec tile, bf16, granule-swizzled
  __shared__ float red[4];

  const int tid = threadIdx.x;
  const int wave = tid >> 6;
  const int lane = tid & 63;
  const int kgrp = lane >> 4;
  const int lid  = lane & 15;
  const int arow_l = wave * 16 + lid;       // LDS-local A row for stages 2,3
  const int rowA = rbase + arow_l;
  const bool av = rowA < jb.M;

  // ---- stage 1: fused = Z @ V  (K=192, N=128) ----
  s8vec az[6];
#pragma unroll
  for (int kt = 0; kt < 6; ++kt) {
    s8vec fr = {0, 0, 0, 0, 0, 0, 0, 0};
    if (av) fr = *(const s8vec*)(jb.Z + (size_t)rowA * 192 + kt * 32 + kgrp * 8);
    az[kt] = fr;
  }
#pragma unroll
  for (int t = 0; t < 8; ++t) {
    f4vec acc = {0.f, 0.f, 0.f, 0.f};
    const int bn = t * 16 + lid;
    const u16* brow = jb.VT + (size_t)bn * 192;
#pragma unroll
    for (int kt = 0; kt < 6; ++kt)
      acc = __builtin_amdgcn_mfma_f32_16x16x32_bf16(az[kt], *(const s8vec*)(brow + kt * 32 + kgrp * 8), acc, 0, 0, 0);
    const int g = bn >> 3;
#pragma unroll
    for (int j = 0; j < 4; ++j) {
      int rl = wave * 16 + kgrp * 4 + j;
      int r = rbase + rl;
      float v = acc[j];
      int gs = (g & 8) | ((g ^ rl) & 7);
      if (r < jb.M) {
        jb.fused[(size_t)r * 128 + bn] = v;
        ftile[rl * 128 + gs * 8 + (bn & 7)] = f2bf(v);
      } else {
        ftile[rl * 128 + gs * 8 + (bn & 7)] = 0;
      }
    }
  }
  __syncthreads();

  // ---- stage 2: zrec = fused @ Vr  (K=128, N=192) ----
  s8vec af[4];
#pragma unroll
  for (int kt = 0; kt < 4; ++kt) {
    int ga = kt * 4 + kgrp;
    int gs = (ga & 8) | ((ga ^ arow_l) & 7);
    af[kt] = *(const s8vec*)(&ftile[arow_l * 128 + gs * 8]);
  }
#pragma unroll
  for (int t = 0; t < 12; ++t) {
    f4vec acc = {0.f, 0.f, 0.f, 0.f};
    const int bn = t * 16 + lid;
    const u16* brow = jb.VRT + (size_t)bn * 128;
#pragma unroll
    for (int kt = 0; kt < 4; ++kt)
      acc = __builtin_amdgcn_mfma_f32_16x16x32_bf16(af[kt], *(const s8vec*)(brow + kt * 32 + kgrp * 8), acc, 0, 0, 0);
    const int g = bn >> 3;
#pragma unroll
    for (int j = 0; j < 4; ++j) {
      int rl = wave * 16 + kgrp * 4 + j;
      int gs = (g & ~7) | ((g ^ rl) & 7);
      ztile[rl * 192 + gs * 8 + (bn & 7)] = f2bf(acc[j]);
    }
  }
  __syncthreads();

  // ---- stage 3: per p, h_rec = zrec[:,p] @ fcr[p]  (K=64, N=128), sqdiff ----
  float sqsum = 0.0f;
#pragma unroll
  for (int p = 0; p < 3; ++p) {
    s8vec aq[2];
#pragma unroll
    for (int kt = 0; kt < 2; ++kt) {
      int ga = p * 8 + kt * 4 + kgrp;
      int gs = (ga & ~7) | ((ga ^ arow_l) & 7);
      aq[kt] = *(const s8vec*)(&ztile[arow_l * 192 + gs * 8]);
    }
    const u16* fp = jb.FCRT + (size_t)p * 128 * 64;
    const u16* tgt = jb.target + (size_t)p * jb.M * 128;
#pragma unroll
    for (int t = 0; t < 8; ++t) {
      f4vec acc = {0.f, 0.f, 0.f, 0.f};
      const int bn = t * 16 + lid;
      const u16* brow = fp + (size_t)bn * 64;
#pragma unroll
      for (int kt = 0; kt < 2; ++kt)
        acc = __builtin_amdgcn_mfma_f32_16x16x32_bf16(aq[kt], *(const s8vec*)(brow + kt * 32 + kgrp * 8), acc, 0, 0, 0);
#pragma unroll
      for (int j = 0; j < 4; ++j) {
        int r = rbase + wave * 16 + kgrp * 4 + j;
        if (r < jb.M) {
          float dd = acc[j] - bf2f(tgt[(size_t)r * 128 + bn]);
          sqsum += dd * dd;
        }
      }
    }
  }
#pragma unroll
  for (int off = 32; off > 0; off >>= 1) sqsum += __shfl_down(sqsum, off);
  if (lane == 0) red[wave] = sqsum;
  __syncthreads();
  if (tid == 0) atomicAdd(jb.loss, red[0] + red[1] + red[2] + red[3]);
}

// ---------------------------------------------------------------------------
// Gram via MFMA, both layers: y = layer*3 + pair
#define GRAM_NKB 40
__global__ __launch_bounds__(256) void gram_k(
    const u16* __restrict__ zt0, const u16* __restrict__ zt1,
    int NP0, int NP1, float* __restrict__ G) {
  const int layer = blockIdx.y / 3;
  const int pair = blockIdx.y % 3;
  const u16* zt = layer ? zt1 : zt0;
  const int NP = layer ? NP1 : NP0;
  const int p = (pair == 2) ? 1 : 0;
  const int q = (pair == 0) ? 1 : 2;
  const int wave = threadIdx.x >> 6;
  const int lane = threadIdx.x & 63;
  const int kgrp = lane >> 4, lid = lane & 15;

  const int KC = (((NP + GRAM_NKB - 1) / GRAM_NKB) + 31) & ~31;
  const int kbeg = blockIdx.x * KC;
  const int kend = min(NP, kbeg + KC);

  const u16* arow = zt + (size_t)(p * 64 + wave * 16 + lid) * NP;
  const u16* brow0 = zt + (size_t)(q * 64 + 0 * 16 + lid) * NP;
  const u16* brow1 = zt + (size_t)(q * 64 + 1 * 16 + lid) * NP;
  const u16* brow2 = zt + (size_t)(q * 64 + 2 * 16 + lid) * NP;
  const u16* brow3 = zt + (size_t)(q * 64 + 3 * 16 + lid) * NP;

  f4vec acc0 = {0.f, 0.f, 0.f, 0.f};
  f4vec acc1 = {0.f, 0.f, 0.f, 0.f};
  f4vec acc2 = {0.f, 0.f, 0.f, 0.f};
  f4vec acc3 = {0.f, 0.f, 0.f, 0.f};

  for (int k0 = kbeg; k0 < kend; k0 += 32) {
    const int ko = k0 + kgrp * 8;
    s8vec af = *(const s8vec*)(arow + ko);
    s8vec b0 = *(const s8vec*)(brow0 + ko);
    s8vec b1 = *(const s8vec*)(brow1 + ko);
    s8vec b2 = *(const s8vec*)(brow2 + ko);
    s8vec b3 = *(const s8vec*)(brow3 + ko);
    acc0 = __builtin_amdgcn_mfma_f32_16x16x32_bf16(af, b0, acc0, 0, 0, 0);
    acc1 = __builtin_amdgcn_mfma_f32_16x16x32_bf16(af, b1, acc1, 0, 0, 0);
    acc2 = __builtin_amdgcn_mfma_f32_16x16x32_bf16(af, b2, acc2, 0, 0, 0);
    acc3 = __builtin_amdgcn_mfma_f32_16x16x32_bf16(af, b3, acc3, 0, 0, 0);
  }

  float* g = G + (size_t)layer * 3 * 4096 + (size_t)pair * 4096;
  const int mrow = wave * 16 + kgrp * 4;
#pragma unroll
  for (int j = 0; j < 4; ++j) {
    atomicAdd(&g[(mrow + j) * 64 + 0 * 16 + lid], acc0[j]);
    atomicAdd(&g[(mrow + j) * 64 + 1 * 16 + lid], acc1[j]);
    atomicAdd(&g[(mrow + j) * 64 + 2 * 16 + lid], acc2[j]);
    atomicAdd(&g[(mrow + j) * 64 + 3 * 16 + lid], acc3[j]);
  }
}

// ---------------------------------------------------------------------------
__global__ __launch_bounds__(256) void loss_k(
    const float* __restrict__ G, const float* __restrict__ RE,
    float* __restrict__ out) {
  float s = 0.f;
  for (int i = threadIdx.x; i < 2 * 3 * 4096; i += 256) { float g = G[i]; s += g * g; }
#pragma unroll
  for (int off = 32; off > 0; off >>= 1) s += __shfl_down(s, off);
  __shared__ float red[4];
  int wave = threadIdx.x >> 6, lane = threadIdx.x & 63;
  if (lane == 0) red[wave] = s;
  __syncthreads();
  if (threadIdx.x == 0) {
    float orth = (red[0] + red[1] + red[2] + red[3]) / 4096.0f;
    float loss = orth + RE[0] / (50000.0f * 128.0f) + RE[1] / (80000.0f * 128.0f);
    out[0] = loss;
  }
}

// ---------------------------------------------------------------------------
static const int COUNTS_H[3] = {50000, 80000, 10000};
static const int OFFS_H[3]   = {0, 50000, 130000};
static const int GRP_H[5]    = {2, 1, 1, 2, 1};                // GCN_GROUP
static const int HOPN[14] = {80000, 50000, 80000, 10000, 80000, 50000, 50000,
                             50000, 80000, 10000, 80000, 50000, 50000, 80000};

extern "C" void kernel_launch(void* const* d_in, const int* in_sizes, int n_in,
                              void* d_out, int out_size, void* d_ws, size_t ws_size,
                              hipStream_t stream) {
  (void)in_sizes; (void)n_in; (void)out_size; (void)ws_size;

  const float* features = (const float*)d_in[0];
  const int* e_user   = (const int*)d_in[1];
  const int* e_item   = (const int*)d_in[2];
  const int* perm_u   = (const int*)d_in[3];
  const int* perm_i   = (const int*)d_in[4];
  const float* W_type = (const float*)d_in[5];
  const float* b_type = (const float*)d_in[6];
  const float* comp   = (const float*)d_in[7];
  const float* W_gcn  = (const float*)d_in[8];
  const float* b_gcn  = (const float*)d_in[9];
  const float* fc[2]  = {(const float*)d_in[10], (const float*)d_in[14]};
  const float* fcr[2] = {(const float*)d_in[11], (const float*)d_in[15]};
  const float* V[2]   = {(const float*)d_in[12], (const float*)d_in[16]};
  const float* Vr[2]  = {(const float*)d_in[13], (const float*)d_in[17]};
  float* out = (float*)d_out;

  char* base = (char*)d_ws;
  size_t off = 0;
  auto alloc = [&](size_t b) -> void* {
    void* p = base + off;
    off = (off + b + 255) & ~(size_t)255;
    return p;
  };
  u16* TF    = (u16*)alloc(140000ull * 128 * 2);      // ZT1 aliases (30.7 <= 35.8 MB)
  u16* HB    = (u16*)alloc(330000ull * 128 * 2);      // chain bufs; BP early; Z0/Z1 late
  u16* OUTSu = (u16*)alloc(3ull * 50000 * 128 * 2);
  u16* OUTSi = (u16*)alloc(3ull * 80000 * 128 * 2);
  int* HISTA    = (int*)alloc(14ull * HSTRIDE * 4);   // ZT0 aliases from here
  int* ROWPTR14 = (int*)alloc(14ull * RP_STRIDE * 4);
  int* ESRC14   = (int*)alloc(14ull * E_EDGES * 4);
  int* IPERM    = (int*)alloc(130000ull * 4);         // [user 50k][item 80k]
  u16* WT_TYPE = (u16*)alloc(3ull * 128 * 256 * 2);
  u16* BT_HOP  = (u16*)alloc(5ull * 128 * 128 * 2);
  u16* FCT     = (u16*)alloc(6ull * 64 * 128 * 2);
  u16* VT      = (u16*)alloc(2ull * 128 * 192 * 2);
  u16* VRT     = (u16*)alloc(2ull * 192 * 128 * 2);
  u16* FCRT    = (u16*)alloc(6ull * 128 * 64 * 2);
  float* G   = (float*)alloc((2 * 3 * 4096 + 2) * 4);
  float* RE  = G + 2 * 3 * 4096;

  // aliases (lifetimes disjoint):
  u32* BP   = (u32*)HB;              // 28 MB; dead before hop L0
  u16* Z0   = HB;                    // [50000][192], fusion phase
  u16* Z1   = HB + 9600000ull;       // [80000][192]
  const int NP0 = 50016, NP1 = 80032;
  u16* ZT0  = (u16*)HISTA;           // 192*50016*2 = 19.2 MB <= CSR block 33.6 MB
  u16* ZT1  = TF;                    // 192*80032*2 = 30.7 MB <= 35.8 MB

  const int hbrow[7] = {0, 80000, 160000, 170000, 220000, 230000, 280000};
  auto HBp = [&](int c) { return HB + (size_t)hbrow[c] * 128; };
  auto RP  = [&](int g) { return ROWPTR14 + (size_t)g * RP_STRIDE; };
  auto ES  = [&](int g) { return ESRC14 + (size_t)g * E_EDGES; };
  auto BT  = [&](int et) { return BT_HOP + (size_t)et * 128 * 128; };
  auto BG  = [&](int et) { return b_gcn + (size_t)GRP_H[et] * 128; };

  // ---- batched weight transposes (24 jobs) --------------------------------
  TBatch tb;
  int tj = 0;
  for (int t = 0; t < 3; ++t)
    tb.j[tj++] = {W_type + (size_t)t * 256 * 128, WT_TYPE + (size_t)t * 128 * 256, nullptr, 256, 128};
  for (int et = 0; et < 5; ++et)
    tb.j[tj++] = {W_gcn + (size_t)GRP_H[et] * 128 * 128, BT_HOP + (size_t)et * 128 * 128,
                  comp + (size_t)et * 128, 128, 128};
  for (int L = 0; L < 2; ++L)
    for (int p = 0; p < 3; ++p)
      tb.j[tj++] = {fc[L] + (size_t)p * 128 * 64, FCT + (size_t)(L * 3 + p) * 64 * 128, nullptr, 128, 64};
  for (int L = 0; L < 2; ++L)
    for (int p = 0; p < 3; ++p)
      tb.j[tj++] = {fcr[L] + (size_t)p * 64 * 128, FCRT + (size_t)(L * 3 + p) * 128 * 64, nullptr, 64, 128};
  for (int L = 0; L < 2; ++L)
    tb.j[tj++] = {V[L], VT + (size_t)L * 128 * 192, nullptr, 192, 128};
  for (int L = 0; L < 2; ++L)
    tb.j[tj++] = {Vr[L], VRT + (size_t)L * 192 * 128, nullptr, 128, 192};
  transpose_b_k<<<dim3(128, 24), 256, 0, stream>>>(tb);

  // ---- inverse perms -------------------------------------------------------
  IBatch ib;
  ib.perm[0] = perm_u; ib.ip[0] = IPERM;          ib.n[0] = 50000;
  ib.perm[1] = perm_i; ib.ip[1] = IPERM + 50000;  ib.n[1] = 80000;
  iperm_b_k<<<dim3(313, 2), 256, 0, stream>>>(ib);

  // ---- CSR build for all 14 hops (two-level bucket sort, no global atomics)
  CsrP cpp;
  for (int g = 0; g < 14; ++g) {
    cpp.n[g] = HOPN[g];
    cpp.sh[g] = (HOPN[g] <= 10000) ? 6 : 8;
    cpp.P[g] = (HOPN[g] + (1 << cpp.sh[g]) - 1) >> cpp.sh[g];
  }
  csr_hist_k<<<dim3(NCH, 14), 256, 0, stream>>>(e_user, e_item, HISTA, cpp);
  csr_scan_k<<<dim3(14), 256, 0, stream>>>(HISTA, cpp);
  csr_scatter_k<<<dim3(NCH, 14), 256, 0, stream>>>(e_user, e_item, HISTA, BP, cpp);
  csr_fine_k<<<dim3(313, 14), 256, 0, stream>>>(BP, HISTA, ROWPTR14, ESRC14, cpp);
  hipMemsetAsync(G, 0, (2 * 3 * 4096 + 2) * 4, stream);

  // ---- NodeTransform (batched, 3 types) -----------------------------------
  {
    GemmBatch nb = {};
    for (int t = 0; t < 3; ++t)
      nb.j[t] = {features + (size_t)OFFS_H[t] * 256, WT_TYPE + (size_t)t * 128 * 256,
                 b_type + (size_t)t * 128, TF + (size_t)OFFS_H[t] * 128,
                 nullptr, COUNTS_H[t], 0};
    gemm_b_k<256, 128, ACT_RELU, 1, false, false>
        <<<dim3(1250, 3), 256, 0, stream>>>(nb, 256, 128);
  }

  // ---- hops in 4 dependency levels ----------------------------------------
  const u16* TF0 = TF;
  const u16* TF1 = TF + 50000ull * 128;
  const int* IPu = IPERM;
  const int* IPi = IPERM + 50000;

  HopBatch L0, L1, L2, L3;
  L0.j[0] = {TF0, RP(0),  ES(0),  BT(0), BG(0), HBp(0), nullptr, 80000, 0};
  L0.j[1] = {TF0, RP(2),  ES(2),  BT(0), BG(0), HBp(1), nullptr, 80000, 0};
  L0.j[2] = {TF0, RP(6),  ES(6),  BT(4), BG(4), OUTSu + 2ull * 50000 * 128, IPu, 50000, 1};
  L0.j[3] = {TF1, RP(7),  ES(7),  BT(1), BG(1), HBp(3), nullptr, 50000, 0};
  L0.j[4] = {TF1, RP(9),  ES(9),  BT(2), BG(2), HBp(4), nullptr, 10000, 0};
  L0.j[5] = {TF1, RP(11), ES(11), BT(1), BG(1), HBp(5), nullptr, 50000, 0};
  L1.j[0] = {HBp(0), RP(1),  ES(1),  BT(1), BG(1), OUTSu, IPu, 50000, 1};
  L1.j[1] = {HBp(1), RP(3),  ES(3),  BT(2), BG(2), HBp(2), nullptr, 10000, 0};
  L1.j[2] = {HBp(3), RP(8),  ES(8),  BT(0), BG(0), OUTSi, IPi, 80000, 1};
  L1.j[3] = {HBp(4), RP(10), ES(10), BT(3), BG(3), OUTSi + 1ull * 80000 * 128, IPi, 80000, 1};
  L1.j[4] = {HBp(5), RP(12), ES(12), BT(4), BG(4), HBp(6), nullptr, 50000, 0};
  L1.j[5] = L1.j[4];
  L2.j[0] = {HBp(2), RP(4),  ES(4),  BT(3), BG(3), HBp(0), nullptr, 80000, 0};
  L2.j[1] = {HBp(6), RP(13), ES(13), BT(0), BG(0), OUTSi + 2ull * 80000 * 128, IPi, 80000, 1};
  L2.j[2] = L2.j[1]; L2.j[3] = L2.j[1]; L2.j[4] = L2.j[1]; L2.j[5] = L2.j[1];
  L3.j[0] = {HBp(0), RP(5), ES(5), BT(1), BG(1), OUTSu + 1ull * 50000 * 128, IPu, 50000, 1};
  L3.j[1] = L3.j[0]; L3.j[2] = L3.j[0]; L3.j[3] = L3.j[0]; L3.j[4] = L3.j[0]; L3.j[5] = L3.j[0];

  hop_b_k<<<dim3(1250, 6), 256, 0, stream>>>(L0);
  hop_b_k<<<dim3(1250, 5), 256, 0, stream>>>(L1);
  hop_b_k<<<dim3(1250, 2), 256, 0, stream>>>(L2);
  hop_b_k<<<dim3(782, 1), 256, 0, stream>>>(L3);

  // ---- fusion (both layers batched) ---------------------------------------
  hipMemsetAsync(ZT0, 0, (size_t)192 * NP0 * 2, stream);
  hipMemsetAsync(ZT1, 0, (size_t)192 * NP1 * 2, stream);

  {
    GemmBatch fb = {};
    for (int p = 0; p < 3; ++p) {
      fb.j[p]     = {OUTSu + (size_t)p * 50000 * 128, FCT + (size_t)p * 64 * 128, nullptr,
                     Z0 + p * 64, ZT0 + (size_t)p * 64 * NP0, 50000, NP0};
      fb.j[p + 3] = {OUTSi + (size_t)p * 80000 * 128, FCT + (size_t)(3 + p) * 64 * 128, nullptr,
                     Z1 + p * 64, ZT1 + (size_t)p * 64 * NP1, 80000, NP1};
    }
    gemm_b_k<128, 64, ACT_TANH, 0, false, true>
        <<<dim3(1250, 6), 256, 0, stream>>>(fb, 128, 192);
  }

  gram_k<<<dim3(GRAM_NKB, 6), 256, 0, stream>>>(ZT0, ZT1, NP0, NP1, G);

  {
    VFJob j0 = {Z0, VT, VRT, FCRT, OUTSu, out, RE + 0, 50000};
    VFJob j1 = {Z1, VT + (size_t)128 * 192, VRT + (size_t)192 * 128, FCRT + (size_t)3 * 128 * 64,
                OUTSi, out + 6400000, RE + 1, 80000};
    vfuse_k<<<dim3(1250, 2), 256, 0, stream>>>(j0, j1);
  }

  loss_k<<<1, 256, 0, stream>>>(G, RE, out + 16640000);
}

// Round 15
// 1038.589 us; speedup vs baseline: 1.1181x; 1.0042x over previous
//
#include <hip/hip_runtime.h>

typedef unsigned short u16;
typedef unsigned int   u32;

#define ACT_NONE 0
#define ACT_RELU 1
#define ACT_TANH 2

#define E_EDGES 500000
#define RP_STRIDE 80004   // per-hop stride for rowptr (ints, 16B-aligned)
#define NCH 62            // edge chunks per hop (8192 edges each)
#define CH 8192
#define HSTRIDE 19456     // per-hop stride in HISTA (>= maxP(313)*NCH(62)=19406)

using s8vec = __attribute__((ext_vector_type(8))) short;   // 8 bf16 (4 VGPRs) MFMA A/B frag
using f4vec = __attribute__((ext_vector_type(4))) float;   // MFMA C/D frag

__device__ __forceinline__ float bf2f(u16 u) {
  union { u32 b; float f; } v; v.b = ((u32)u) << 16; return v.f;
}
__device__ __forceinline__ u16 f2bf(float x) {
  union { float f; u32 b; } v; v.f = x;
  u32 r = v.b + 0x7fffu + ((v.b >> 16) & 1u);   // round-to-nearest-even
  return (u16)(r >> 16);
}
__device__ __forceinline__ void acc8(float* acc, uint4 v) {
  union { u32 b; float f; } cv;
  cv.b = v.x << 16;         acc[0] += cv.f;
  cv.b = v.x & 0xffff0000u; acc[1] += cv.f;
  cv.b = v.y << 16;         acc[2] += cv.f;
  cv.b = v.y & 0xffff0000u; acc[3] += cv.f;
  cv.b = v.z << 16;         acc[4] += cv.f;
  cv.b = v.z & 0xffff0000u; acc[5] += cv.f;
  cv.b = v.w << 16;         acc[6] += cv.f;
  cv.b = v.w & 0xffff0000u; acc[7] += cv.f;
}

// ---------------------------------------------------------------------------
// batched transpose + cast f32->bf16 (+ optional per-row scale): in[R][C]->out[C][R]
struct TJob { const float* src; u16* dst; const float* scale; int R; int C; };
struct TBatch { TJob j[24]; };
__global__ __launch_bounds__(256) void transpose_b_k(TBatch b) {
  TJob jb = b.j[blockIdx.y];
  int i = blockIdx.x * 256 + threadIdx.x;
  if (i >= jb.R * jb.C) return;
  int r = i / jb.C, c = i % jb.C;
  float v = jb.src[i];
  if (jb.scale) v *= jb.scale[r];
  jb.dst[(size_t)c * jb.R + r] = f2bf(v);
}

// ---------------------------------------------------------------------------
// batched inverse permutation: ip[perm[i]] = i
struct IBatch { const int* perm[2]; int* ip[2]; int n[2]; };
__global__ __launch_bounds__(256) void iperm_b_k(IBatch b) {
  int y = blockIdx.y;
  int i = blockIdx.x * 256 + threadIdx.x;
  if (i < b.n[y]) b.ip[y][b.perm[y][i]] = i;
}

// ---------------------------------------------------------------------------
// Two-level bucket CSR build over 14 hops — ZERO global atomics.
struct CsrP { int n[14]; int sh[14]; int P[14]; };

__global__ __launch_bounds__(256) void csr_hist_k(
    const int* __restrict__ eu, const int* __restrict__ ei,
    int* __restrict__ hista, CsrP cp) {
  const int hop = blockIdx.y, chunk = blockIdx.x;
  const int P = cp.P[hop], sh = cp.sh[hop];
  __shared__ int hist[320];
  for (int i = threadIdx.x; i < P; i += 256) hist[i] = 0;
  __syncthreads();
  const int* edges = (hop < 7) ? eu : ei;
  const int h7 = (hop < 7) ? hop : hop - 7;
  const int* dstp = edges + (size_t)(h7 * 2 + 1) * E_EDGES;
  const int e0 = chunk * CH;
  const int e1 = min(E_EDGES, e0 + CH);
  for (int e = e0 + threadIdx.x * 4; e < e1; e += 1024) {
    int4 d4 = *(const int4*)(dstp + e);
    atomicAdd(&hist[d4.x >> sh], 1);
    atomicAdd(&hist[d4.y >> sh], 1);
    atomicAdd(&hist[d4.z >> sh], 1);
    atomicAdd(&hist[d4.w >> sh], 1);
  }
  __syncthreads();
  for (int i = threadIdx.x; i < P; i += 256)
    hista[(size_t)hop * HSTRIDE + i * NCH + chunk] = hist[i];
}

__global__ __launch_bounds__(256) void csr_scan_k(int* __restrict__ hista, CsrP cp) {
  const int hop = blockIdx.x;
  const int L = cp.P[hop] * NCH;
  int* a = hista + (size_t)hop * HSTRIDE;
  const int per = (L + 255) >> 8;
  const int lo = threadIdx.x * per;
  const int hi = min(L, lo + per);
  int s = 0;
  for (int i = lo; i < hi; ++i) s += a[i];
  __shared__ int lds[256];
  lds[threadIdx.x] = s;
  __syncthreads();
  for (int off = 1; off < 256; off <<= 1) {
    int v = (threadIdx.x >= off) ? lds[threadIdx.x - off] : 0;
    __syncthreads();
    lds[threadIdx.x] += v;
    __syncthreads();
  }
  int run = threadIdx.x ? lds[threadIdx.x - 1] : 0;
  for (int i = lo; i < hi; ++i) { int v = a[i]; a[i] = run; run += v; }
}

__global__ __launch_bounds__(256) void csr_scatter_k(
    const int* __restrict__ eu, const int* __restrict__ ei,
    const int* __restrict__ hista, u32* __restrict__ bp, CsrP cp) {
  const int hop = blockIdx.y, chunk = blockIdx.x;
  const int P = cp.P[hop], sh = cp.sh[hop];
  const u32 fm = (1u << sh) - 1u;
  __shared__ int cur[320];
  for (int i = threadIdx.x; i < P; i += 256)
    cur[i] = hista[(size_t)hop * HSTRIDE + i * NCH + chunk];
  __syncthreads();
  const int* edges = (hop < 7) ? eu : ei;
  const int h7 = (hop < 7) ? hop : hop - 7;
  const int* srcp = edges + (size_t)(h7 * 2) * E_EDGES;
  const int* dstp = srcp + E_EDGES;
  u32* b = bp + (size_t)hop * E_EDGES;
  const int e0 = chunk * CH;
  const int e1 = min(E_EDGES, e0 + CH);
  for (int e = e0 + threadIdx.x * 4; e < e1; e += 1024) {
    int4 d4 = *(const int4*)(dstp + e);
    int4 s4 = *(const int4*)(srcp + e);
    int dd[4] = {d4.x, d4.y, d4.z, d4.w};
    int ss[4] = {s4.x, s4.y, s4.z, s4.w};
#pragma unroll
    for (int j = 0; j < 4; ++j) {
      int pos = atomicAdd(&cur[dd[j] >> sh], 1);   // LDS atomic
      b[pos] = (u32)ss[j] | (((u32)dd[j] & fm) << 24);
    }
  }
}

__global__ __launch_bounds__(256) void csr_fine_k(
    const u32* __restrict__ bp, const int* __restrict__ hista,
    int* __restrict__ rowptrb, int* __restrict__ esrcb, CsrP cp) {
  const int hop = blockIdx.y, p = blockIdx.x;
  const int P = cp.P[hop];
  if (p >= P) return;
  const int n = cp.n[hop], sh = cp.sh[hop], W = 1 << sh;
  const int* fl = hista + (size_t)hop * HSTRIDE;
  const int beg = fl[p * NCH];
  const int end = (p + 1 < P) ? fl[(p + 1) * NCH] : E_EDGES;
  const int nb = min(W, n - p * W);
  const int tid = threadIdx.x;

  __shared__ int fh[256];
  __shared__ int sc[256];
  __shared__ int cur[256];
  fh[tid] = 0;
  __syncthreads();
  const u32* b = bp + (size_t)hop * E_EDGES;
  for (int i = beg + tid; i < end; i += 256)
    atomicAdd(&fh[b[i] >> 24], 1);
  __syncthreads();
  sc[tid] = fh[tid];
  __syncthreads();
  for (int off = 1; off < 256; off <<= 1) {
    int v = (tid >= off) ? sc[tid - off] : 0;
    __syncthreads();
    sc[tid] += v;
    __syncthreads();
  }
  const int excl = tid ? sc[tid - 1] : 0;
  int* rowptr = rowptrb + (size_t)hop * RP_STRIDE;
  if (tid < nb) rowptr[p * W + tid] = beg + excl;
  cur[tid] = beg + excl;
  if (p == P - 1 && tid == 0) rowptr[n] = E_EDGES;
  __syncthreads();
  int* esrc = esrcb + (size_t)hop * E_EDGES;
  for (int i = beg + tid; i < end; i += 256) {
    u32 v = b[i];
    int pos = atomicAdd(&cur[v >> 24], 1);        // LDS atomic
    esrc[pos] = (int)(v & 0xFFFFFFu);
  }
}

// ---------------------------------------------------------------------------
// Level-batched fused hop kernel (R10 config: LDS B-tile, 2-deep gather)
struct HopJob {
  const u16* h; const int* rowptr; const int* esrc;
  const u16* Bt; const float* bias; u16* out;
  const int* iperm; int n; int permout;
};
struct HopBatch { HopJob j[6]; };

__global__ __launch_bounds__(256) void hop_b_k(HopBatch batch) {
  const HopJob jb = batch.j[blockIdx.y];
  const int rbase = blockIdx.x * 64;
  if (rbase >= jb.n) return;

  __shared__ u16 bts[128 * 128];
  const int tid = threadIdx.x;
  // stage Bt[128][128] -> LDS with 16B-granule XOR swizzle
  for (int i = tid; i < 128 * 16; i += 256) {
    int nn = i >> 4, g = i & 15;
    int gs = (g & 8) | ((g ^ nn) & 7);
    *(uint4*)(&bts[nn * 128 + gs * 8]) = *(const uint4*)(jb.Bt + (size_t)nn * 128 + g * 8);
  }
  __syncthreads();

  const int wave = tid >> 6;
  const int lane = tid & 63;
  const int kgrp = lane >> 4;
  const int lid  = lane & 15;
  const int d = rbase + wave * 16 + lid;

  float a0[8] = {0,0,0,0,0,0,0,0}, a1[8] = {0,0,0,0,0,0,0,0};
  float a2[8] = {0,0,0,0,0,0,0,0}, a3[8] = {0,0,0,0,0,0,0,0};
  int s0 = 0, s1 = 0;
  if (d < jb.n) { s0 = jb.rowptr[d]; s1 = jb.rowptr[d + 1]; }
  const u16* hk = jb.h + kgrp * 8;
  int i = s0;
  for (; i + 1 < s1; i += 2) {
    const u16* ra = hk + (size_t)jb.esrc[i] * 128;
    const u16* rb = hk + (size_t)jb.esrc[i + 1] * 128;
    uint4 va0 = *(const uint4*)(ra);      uint4 vb0 = *(const uint4*)(rb);
    uint4 va1 = *(const uint4*)(ra + 32); uint4 vb1 = *(const uint4*)(rb + 32);
    uint4 va2 = *(const uint4*)(ra + 64); uint4 vb2 = *(const uint4*)(rb + 64);
    uint4 va3 = *(const uint4*)(ra + 96); uint4 vb3 = *(const uint4*)(rb + 96);
    acc8(a0, va0); acc8(a1, va1); acc8(a2, va2); acc8(a3, va3);
    acc8(a0, vb0); acc8(a1, vb1); acc8(a2, vb2); acc8(a3, vb3);
  }
  if (i < s1) {
    const u16* ra = hk + (size_t)jb.esrc[i] * 128;
    acc8(a0, *(const uint4*)(ra));
    acc8(a1, *(const uint4*)(ra + 32));
    acc8(a2, *(const uint4*)(ra + 64));
    acc8(a3, *(const uint4*)(ra + 96));
  }
  const float rs = 1.0f / fmaxf((float)(s1 - s0), 1.0f);
  s8vec f0, f1, f2, f3;
#pragma unroll
  for (int j = 0; j < 8; ++j) f0[j] = (short)f2bf(a0[j] * rs);
#pragma unroll
  for (int j = 0; j < 8; ++j) f1[j] = (short)f2bf(a1[j] * rs);
#pragma unroll
  for (int j = 0; j < 8; ++j) f2[j] = (short)f2bf(a2[j] * rs);
#pragma unroll
  for (int j = 0; j < 8; ++j) f3[j] = (short)f2bf(a3[j] * rs);

  int rout[4];
#pragma unroll
  for (int j = 0; j < 4; ++j) {
    int rv = rbase + wave * 16 + kgrp * 4 + j;
    rout[j] = (rv < jb.n) ? (jb.permout ? jb.iperm[rv] : rv) : -1;
  }

#pragma unroll
  for (int t = 0; t < 8; ++t) {
    f4vec c = {0.f, 0.f, 0.f, 0.f};
    const int bn = t * 16 + lid;
    int g = kgrp;
    int gs = (g & 8) | ((g ^ bn) & 7);
    c = __builtin_amdgcn_mfma_f32_16x16x32_bf16(f0, *(const s8vec*)(&bts[bn * 128 + gs * 8]), c, 0, 0, 0);
    g = 4 + kgrp; gs = (g & 8) | ((g ^ bn) & 7);
    c = __builtin_amdgcn_mfma_f32_16x16x32_bf16(f1, *(const s8vec*)(&bts[bn * 128 + gs * 8]), c, 0, 0, 0);
    g = 8 + kgrp; gs = (g & 8) | ((g ^ bn) & 7);
    c = __builtin_amdgcn_mfma_f32_16x16x32_bf16(f2, *(const s8vec*)(&bts[bn * 128 + gs * 8]), c, 0, 0, 0);
    g = 12 + kgrp; gs = (g & 8) | ((g ^ bn) & 7);
    c = __builtin_amdgcn_mfma_f32_16x16x32_bf16(f3, *(const s8vec*)(&bts[bn * 128 + gs * 8]), c, 0, 0, 0);
    const float bb = jb.bias[bn];
#pragma unroll
    for (int j = 0; j < 4; ++j) {
      if (rout[j] >= 0) {
        float v = c[j] + bb;
        jb.out[(size_t)rout[j] * 128 + bn] = f2bf(v);
      }
    }
  }
}

// ---------------------------------------------------------------------------
// Batched MFMA GEMM: C[M][N] = act(A[M][K] @ B[K][N] + bias); Bt=[N][K] bf16.
struct GemmJob {
  const void* A; const u16* Bt; const float* bias; void* C;
  u16* Ct; int M; int ldCt;
};
struct GemmBatch { GemmJob j[6]; };

template <int K, int N, int ACT, int AMODE, bool CF32, bool CTR>
__global__ __launch_bounds__(256) void gemm_b_k(
    GemmBatch batch, int ldA, int ldC) {
  static_assert(K % 32 == 0 && N % 16 == 0, "");
  const GemmJob jb = batch.j[blockIdx.y];
  const int rbase0 = blockIdx.x * 64;
  if (rbase0 >= jb.M) return;

  __shared__ u16 bts[N * K];

  const int tid = threadIdx.x;
  for (int i = tid; i < N * (K / 8); i += 256) {
    int n = i / (K / 8);
    int g = i % (K / 8);
    int gs = (g & ~7) | ((g ^ n) & 7);
    *(uint4*)(&bts[n * K + gs * 8]) = *(const uint4*)(jb.Bt + (size_t)n * K + g * 8);
  }
  __syncthreads();

  const int wave = tid >> 6;
  const int lane = tid & 63;
  const int kgrp = lane >> 4;
  const int rbase = rbase0 + wave * 16;
  const int rowA = rbase + (lane & 15);
  const bool av = rowA < jb.M;

  s8vec afr[K / 32];
  if constexpr (AMODE == 1) {
    const float* arow = (const float*)jb.A + (size_t)rowA * ldA;
#pragma unroll
    for (int kt = 0; kt < K / 32; ++kt) {
      s8vec fr = {0, 0, 0, 0, 0, 0, 0, 0};
      if (av) {
        const float* p = arow + kt * 32 + kgrp * 8;
        float4 fa = *(const float4*)(p);
        float4 fb = *(const float4*)(p + 4);
        fr[0] = (short)f2bf(fa.x); fr[1] = (short)f2bf(fa.y);
        fr[2] = (short)f2bf(fa.z); fr[3] = (short)f2bf(fa.w);
        fr[4] = (short)f2bf(fb.x); fr[5] = (short)f2bf(fb.y);
        fr[6] = (short)f2bf(fb.z); fr[7] = (short)f2bf(fb.w);
      }
      afr[kt] = fr;
    }
  } else {
    const u16* arow = (const u16*)jb.A + (size_t)rowA * ldA;
#pragma unroll
    for (int kt = 0; kt < K / 32; ++kt) {
      s8vec fr = {0, 0, 0, 0, 0, 0, 0, 0};
      if (av) fr = *(const s8vec*)(arow + kt * 32 + kgrp * 8);
      afr[kt] = fr;
    }
  }

#pragma unroll
  for (int t = 0; t < N / 16; ++t) {
    f4vec acc = {0.f, 0.f, 0.f, 0.f};
    const int bn = t * 16 + (lane & 15);
#pragma unroll
    for (int kt = 0; kt < K / 32; ++kt) {
      int g = kt * 4 + kgrp;
      int gs = (g & ~7) | ((g ^ bn) & 7);
      s8vec bfr = *(const s8vec*)(&bts[bn * K + gs * 8]);
      acc = __builtin_amdgcn_mfma_f32_16x16x32_bf16(afr[kt], bfr, acc, 0, 0, 0);
    }
    const int col = t * 16 + (lane & 15);
    float bb = jb.bias ? jb.bias[col] : 0.0f;
#pragma unroll
    for (int j = 0; j < 4; ++j) {
      int r = rbase + kgrp * 4 + j;        // C/D: col=lane&15, row=(lane>>4)*4+j
      if (r < jb.M) {
        float v = acc[j] + bb;
        if constexpr (ACT == ACT_RELU) v = fmaxf(v, 0.0f);
        if constexpr (ACT == ACT_TANH) v = tanhf(v);
        if constexpr (CF32) {
          ((float*)jb.C)[(size_t)r * ldC + col] = v;
        } else {
          ((u16*)jb.C)[(size_t)r * ldC + col] = f2bf(v);
        }
        if constexpr (CTR) {
          jb.Ct[(size_t)col * jb.ldCt + r] = f2bf(v);
        }
      }
    }
  }
}

// ---------------------------------------------------------------------------
// Fused V -> Vr -> fcr+sqdiff (3-stage, per layer). Register-budgeted
// (launch_bounds 256,3: LDS caps at 3 blocks/CU anyway) with t-paired MFMA
// chains: 12 B-fragments issued up front per pair, two independent acc chains.
struct VFJob {
  const u16* Z;      // [M][192]
  const u16* VT;     // [128][192]  (Bt stage1)
  const u16* VRT;    // [192][128]  (Bt stage2)
  const u16* FCRT;   // 3 x [128][64] (Bt stage3)
  const u16* target; // OUTS_L: 3 x [M][128]
  float* fused;      // [M][128] f32 (model output)
  float* loss;       // RE + L
  int M;
};

__global__ __launch_bounds__(256, 3) void vfuse_k(VFJob j0, VFJob j1) {
  const VFJob jb = blockIdx.y ? j1 : j0;
  const int rbase = blockIdx.x * 64;
  if (rbase >= jb.M) return;

  __shared__ u16 ftile[64 * 128];   // fused tile, bf16, granule-swizzled
  __shared__ u16 ztile[64 * 192];   // zrec tile, bf16, granule-swizzled
  __shared__ float red[4];

  const int tid = threadIdx.x;
  const int wave = tid >> 6;
  const int lane = tid & 63;
  const int kgrp = lane >> 4;
  const int lid  = lane & 15;
  const int arow_l = wave * 16 + lid;       // LDS-local A row for stages 2,3
  const int rowA = rbase + arow_l;
  const bool av = rowA < jb.M;

  // ---- stage 1: fused = Z @ V  (K=192, N=128), t-pairs ----
  s8vec az[6];
#pragma unroll
  for (int kt = 0; kt < 6; ++kt) {
    s8vec fr = {0, 0, 0, 0, 0, 0, 0, 0};
    if (av) fr = *(const s8vec*)(jb.Z + (size_t)rowA * 192 + kt * 32 + kgrp * 8);
    az[kt] = fr;
  }
#pragma unroll
  for (int t2 = 0; t2 < 4; ++t2) {
    const int ta = t2 * 2, tb = ta + 1;
    const int bna = ta * 16 + lid, bnb = tb * 16 + lid;
    const u16* browa = jb.VT + (size_t)bna * 192 + kgrp * 8;
    const u16* browb = jb.VT + (size_t)bnb * 192 + kgrp * 8;
    s8vec ba0 = *(const s8vec*)(browa);       s8vec bb0 = *(const s8vec*)(browb);
    s8vec ba1 = *(const s8vec*)(browa + 32);  s8vec bb1 = *(const s8vec*)(browb + 32);
    s8vec ba2 = *(const s8vec*)(browa + 64);  s8vec bb2 = *(const s8vec*)(browb + 64);
    s8vec ba3 = *(const s8vec*)(browa + 96);  s8vec bb3 = *(const s8vec*)(browb + 96);
    s8vec ba4 = *(const s8vec*)(browa + 128); s8vec bb4 = *(const s8vec*)(browb + 128);
    s8vec ba5 = *(const s8vec*)(browa + 160); s8vec bb5 = *(const s8vec*)(browb + 160);
    f4vec ca = {0.f, 0.f, 0.f, 0.f}, cb = {0.f, 0.f, 0.f, 0.f};
    ca = __builtin_amdgcn_mfma_f32_16x16x32_bf16(az[0], ba0, ca, 0, 0, 0);
    cb = __builtin_amdgcn_mfma_f32_16x16x32_bf16(az[0], bb0, cb, 0, 0, 0);
    ca = __builtin_amdgcn_mfma_f32_16x16x32_bf16(az[1], ba1, ca, 0, 0, 0);
    cb = __builtin_amdgcn_mfma_f32_16x16x32_bf16(az[1], bb1, cb, 0, 0, 0);
    ca = __builtin_amdgcn_mfma_f32_16x16x32_bf16(az[2], ba2, ca, 0, 0, 0);
    cb = __builtin_amdgcn_mfma_f32_16x16x32_bf16(az[2], bb2, cb, 0, 0, 0);
    ca = __builtin_amdgcn_mfma_f32_16x16x32_bf16(az[3], ba3, ca, 0, 0, 0);
    cb = __builtin_amdgcn_mfma_f32_16x16x32_bf16(az[3], bb3, cb, 0, 0, 0);
    ca = __builtin_amdgcn_mfma_f32_16x16x32_bf16(az[4], ba4, ca, 0, 0, 0);
    cb = __builtin_amdgcn_mfma_f32_16x16x32_bf16(az[4], bb4, cb, 0, 0, 0);
    ca = __builtin_amdgcn_mfma_f32_16x16x32_bf16(az[5], ba5, ca, 0, 0, 0);
    cb = __builtin_amdgcn_mfma_f32_16x16x32_bf16(az[5], bb5, cb, 0, 0, 0);
#pragma unroll
    for (int half = 0; half < 2; ++half) {
      const int bn = half ? bnb : bna;
      const f4vec c = half ? cb : ca;
      const int g = bn >> 3;
#pragma unroll
      for (int j = 0; j < 4; ++j) {
        int rl = wave * 16 + kgrp * 4 + j;
        int r = rbase + rl;
        int gs = (g & 8) | ((g ^ rl) & 7);
        if (r < jb.M) {
          jb.fused[(size_t)r * 128 + bn] = c[j];
          ftile[rl * 128 + gs * 8 + (bn & 7)] = f2bf(c[j]);
        } else {
          ftile[rl * 128 + gs * 8 + (bn & 7)] = 0;
        }
      }
    }
  }
  __syncthreads();

  // ---- stage 2: zrec = fused @ Vr  (K=128, N=192), t-pairs ----
  s8vec af[4];
#pragma unroll
  for (int kt = 0; kt < 4; ++kt) {
    int ga = kt * 4 + kgrp;
    int gs = (ga & 8) | ((ga ^ arow_l) & 7);
    af[kt] = *(const s8vec*)(&ftile[arow_l * 128 + gs * 8]);
  }
#pragma unroll
  for (int t2 = 0; t2 < 6; ++t2) {
    const int ta = t2 * 2, tb = ta + 1;
    const int bna = ta * 16 + lid, bnb = tb * 16 + lid;
    const u16* browa = jb.VRT + (size_t)bna * 128 + kgrp * 8;
    const u16* browb = jb.VRT + (size_t)bnb * 128 + kgrp * 8;
    s8vec ba0 = *(const s8vec*)(browa);       s8vec bb0 = *(const s8vec*)(browb);
    s8vec ba1 = *(const s8vec*)(browa + 32);  s8vec bb1 = *(const s8vec*)(browb + 32);
    s8vec ba2 = *(const s8vec*)(browa + 64);  s8vec bb2 = *(const s8vec*)(browb + 64);
    s8vec ba3 = *(const s8vec*)(browa + 96);  s8vec bb3 = *(const s8vec*)(browb + 96);
    f4vec ca = {0.f, 0.f, 0.f, 0.f}, cb = {0.f, 0.f, 0.f, 0.f};
    ca = __builtin_amdgcn_mfma_f32_16x16x32_bf16(af[0], ba0, ca, 0, 0, 0);
    cb = __builtin_amdgcn_mfma_f32_16x16x32_bf16(af[0], bb0, cb, 0, 0, 0);
    ca = __builtin_amdgcn_mfma_f32_16x16x32_bf16(af[1], ba1, ca, 0, 0, 0);
    cb = __builtin_amdgcn_mfma_f32_16x16x32_bf16(af[1], bb1, cb, 0, 0, 0);
    ca = __builtin_amdgcn_mfma_f32_16x16x32_bf16(af[2], ba2, ca, 0, 0, 0);
    cb = __builtin_amdgcn_mfma_f32_16x16x32_bf16(af[2], bb2, cb, 0, 0, 0);
    ca = __builtin_amdgcn_mfma_f32_16x16x32_bf16(af[3], ba3, ca, 0, 0, 0);
    cb = __builtin_amdgcn_mfma_f32_16x16x32_bf16(af[3], bb3, cb, 0, 0, 0);
#pragma unroll
    for (int half = 0; half < 2; ++half) {
      const int bn = half ? bnb : bna;
      const f4vec c = half ? cb : ca;
      const int g = bn >> 3;
#pragma unroll
      for (int j = 0; j < 4; ++j) {
        int rl = wave * 16 + kgrp * 4 + j;
        int gs = (g & ~7) | ((g ^ rl) & 7);
        ztile[rl * 192 + gs * 8 + (bn & 7)] = f2bf(c[j]);
      }
    }
  }
  __syncthreads();

  // ---- stage 3: per p, h_rec = zrec[:,p] @ fcr[p]  (K=64, N=128), sqdiff ----
  float sqsum = 0.0f;
#pragma unroll
  for (int p = 0; p < 3; ++p) {
    s8vec aq[2];
#pragma unroll
    for (int kt = 0; kt < 2; ++kt) {
      int ga = p * 8 + kt * 4 + kgrp;
      int gs = (ga & ~7) | ((ga ^ arow_l) & 7);
      aq[kt] = *(const s8vec*)(&ztile[arow_l * 192 + gs * 8]);
    }
    const u16* fp = jb.FCRT + (size_t)p * 128 * 64;
    const u16* tgt = jb.target + (size_t)p * jb.M * 128;
#pragma unroll
    for (int t2 = 0; t2 < 4; ++t2) {
      const int ta = t2 * 2, tb = ta + 1;
      const int bna = ta * 16 + lid, bnb = tb * 16 + lid;
      const u16* browa = fp + (size_t)bna * 64 + kgrp * 8;
      const u16* browb = fp + (size_t)bnb * 64 + kgrp * 8;
      s8vec ba0 = *(const s8vec*)(browa);      s8vec bb0 = *(const s8vec*)(browb);
      s8vec ba1 = *(const s8vec*)(browa + 32); s8vec bb1 = *(const s8vec*)(browb + 32);
      f4vec ca = {0.f, 0.f, 0.f, 0.f}, cb = {0.f, 0.f, 0.f, 0.f};
      ca = __builtin_amdgcn_mfma_f32_16x16x32_bf16(aq[0], ba0, ca, 0, 0, 0);
      cb = __builtin_amdgcn_mfma_f32_16x16x32_bf16(aq[0], bb0, cb, 0, 0, 0);
      ca = __builtin_amdgcn_mfma_f32_16x16x32_bf16(aq[1], ba1, ca, 0, 0, 0);
      cb = __builtin_amdgcn_mfma_f32_16x16x32_bf16(aq[1], bb1, cb, 0, 0, 0);
#pragma unroll
      for (int half = 0; half < 2; ++half) {
        const int bn = half ? bnb : bna;
        const f4vec c = half ? cb : ca;
#pragma unroll
        for (int j = 0; j < 4; ++j) {
          int r = rbase + wave * 16 + kgrp * 4 + j;
          if (r < jb.M) {
            float dd = c[j] - bf2f(tgt[(size_t)r * 128 + bn]);
            sqsum += dd * dd;
          }
        }
      }
    }
  }
#pragma unroll
  for (int off = 32; off > 0; off >>= 1) sqsum += __shfl_down(sqsum, off);
  if (lane == 0) red[wave] = sqsum;
  __syncthreads();
  if (tid == 0) atomicAdd(jb.loss, red[0] + red[1] + red[2] + red[3]);
}

// ---------------------------------------------------------------------------
// Gram via MFMA, both layers: y = layer*3 + pair
#define GRAM_NKB 40
__global__ __launch_bounds__(256) void gram_k(
    const u16* __restrict__ zt0, const u16* __restrict__ zt1,
    int NP0, int NP1, float* __restrict__ G) {
  const int layer = blockIdx.y / 3;
  const int pair = blockIdx.y % 3;
  const u16* zt = layer ? zt1 : zt0;
  const int NP = layer ? NP1 : NP0;
  const int p = (pair == 2) ? 1 : 0;
  const int q = (pair == 0) ? 1 : 2;
  const int wave = threadIdx.x >> 6;
  const int lane = threadIdx.x & 63;
  const int kgrp = lane >> 4, lid = lane & 15;

  const int KC = (((NP + GRAM_NKB - 1) / GRAM_NKB) + 31) & ~31;
  const int kbeg = blockIdx.x * KC;
  const int kend = min(NP, kbeg + KC);

  const u16* arow = zt + (size_t)(p * 64 + wave * 16 + lid) * NP;
  const u16* brow0 = zt + (size_t)(q * 64 + 0 * 16 + lid) * NP;
  const u16* brow1 = zt + (size_t)(q * 64 + 1 * 16 + lid) * NP;
  const u16* brow2 = zt + (size_t)(q * 64 + 2 * 16 + lid) * NP;
  const u16* brow3 = zt + (size_t)(q * 64 + 3 * 16 + lid) * NP;

  f4vec acc0 = {0.f, 0.f, 0.f, 0.f};
  f4vec acc1 = {0.f, 0.f, 0.f, 0.f};
  f4vec acc2 = {0.f, 0.f, 0.f, 0.f};
  f4vec acc3 = {0.f, 0.f, 0.f, 0.f};

  for (int k0 = kbeg; k0 < kend; k0 += 32) {
    const int ko = k0 + kgrp * 8;
    s8vec af = *(const s8vec*)(arow + ko);
    s8vec b0 = *(const s8vec*)(brow0 + ko);
    s8vec b1 = *(const s8vec*)(brow1 + ko);
    s8vec b2 = *(const s8vec*)(brow2 + ko);
    s8vec b3 = *(const s8vec*)(brow3 + ko);
    acc0 = __builtin_amdgcn_mfma_f32_16x16x32_bf16(af, b0, acc0, 0, 0, 0);
    acc1 = __builtin_amdgcn_mfma_f32_16x16x32_bf16(af, b1, acc1, 0, 0, 0);
    acc2 = __builtin_amdgcn_mfma_f32_16x16x32_bf16(af, b2, acc2, 0, 0, 0);
    acc3 = __builtin_amdgcn_mfma_f32_16x16x32_bf16(af, b3, acc3, 0, 0, 0);
  }

  float* g = G + (size_t)layer * 3 * 4096 + (size_t)pair * 4096;
  const int mrow = wave * 16 + kgrp * 4;
#pragma unroll
  for (int j = 0; j < 4; ++j) {
    atomicAdd(&g[(mrow + j) * 64 + 0 * 16 + lid], acc0[j]);
    atomicAdd(&g[(mrow + j) * 64 + 1 * 16 + lid], acc1[j]);
    atomicAdd(&g[(mrow + j) * 64 + 2 * 16 + lid], acc2[j]);
    atomicAdd(&g[(mrow + j) * 64 + 3 * 16 + lid], acc3[j]);
  }
}

// ---------------------------------------------------------------------------
__global__ __launch_bounds__(256) void loss_k(
    const float* __restrict__ G, const float* __restrict__ RE,
    float* __restrict__ out) {
  float s = 0.f;
  for (int i = threadIdx.x; i < 2 * 3 * 4096; i += 256) { float g = G[i]; s += g * g; }
#pragma unroll
  for (int off = 32; off > 0; off >>= 1) s += __shfl_down(s, off);
  __shared__ float red[4];
  int wave = threadIdx.x >> 6, lane = threadIdx.x & 63;
  if (lane == 0) red[wave] = s;
  __syncthreads();
  if (threadIdx.x == 0) {
    float orth = (red[0] + red[1] + red[2] + red[3]) / 4096.0f;
    float loss = orth + RE[0] / (50000.0f * 128.0f) + RE[1] / (80000.0f * 128.0f);
    out[0] = loss;
  }
}

// ---------------------------------------------------------------------------
static const int COUNTS_H[3] = {50000, 80000, 10000};
static const int OFFS_H[3]   = {0, 50000, 130000};
static const int GRP_H[5]    = {2, 1, 1, 2, 1};                // GCN_GROUP
static const int HOPN[14] = {80000, 50000, 80000, 10000, 80000, 50000, 50000,
                             50000, 80000, 10000, 80000, 50000, 50000, 80000};

extern "C" void kernel_launch(void* const* d_in, const int* in_sizes, int n_in,
                              void* d_out, int out_size, void* d_ws, size_t ws_size,
                              hipStream_t stream) {
  (void)in_sizes; (void)n_in; (void)out_size; (void)ws_size;

  const float* features = (const float*)d_in[0];
  const int* e_user   = (const int*)d_in[1];
  const int* e_item   = (const int*)d_in[2];
  const int* perm_u   = (const int*)d_in[3];
  const int* perm_i   = (const int*)d_in[4];
  const float* W_type = (const float*)d_in[5];
  const float* b_type = (const float*)d_in[6];
  const float* comp   = (const float*)d_in[7];
  const float* W_gcn  = (const float*)d_in[8];
  const float* b_gcn  = (const float*)d_in[9];
  const float* fc[2]  = {(const float*)d_in[10], (const float*)d_in[14]};
  const float* fcr[2] = {(const float*)d_in[11], (const float*)d_in[15]};
  const float* V[2]   = {(const float*)d_in[12], (const float*)d_in[16]};
  const float* Vr[2]  = {(const float*)d_in[13], (const float*)d_in[17]};
  float* out = (float*)d_out;

  char* base = (char*)d_ws;
  size_t off = 0;
  auto alloc = [&](size_t b) -> void* {
    void* p = base + off;
    off = (off + b + 255) & ~(size_t)255;
    return p;
  };
  u16* TF    = (u16*)alloc(140000ull * 128 * 2);      // ZT1 aliases (30.7 <= 35.8 MB)
  u16* HB    = (u16*)alloc(330000ull * 128 * 2);      // chain bufs; BP early; Z0/Z1 late
  u16* OUTSu = (u16*)alloc(3ull * 50000 * 128 * 2);
  u16* OUTSi = (u16*)alloc(3ull * 80000 * 128 * 2);
  int* HISTA    = (int*)alloc(14ull * HSTRIDE * 4);   // ZT0 aliases from here
  int* ROWPTR14 = (int*)alloc(14ull * RP_STRIDE * 4);
  int* ESRC14   = (int*)alloc(14ull * E_EDGES * 4);
  int* IPERM    = (int*)alloc(130000ull * 4);         // [user 50k][item 80k]
  u16* WT_TYPE = (u16*)alloc(3ull * 128 * 256 * 2);
  u16* BT_HOP  = (u16*)alloc(5ull * 128 * 128 * 2);
  u16* FCT     = (u16*)alloc(6ull * 64 * 128 * 2);
  u16* VT      = (u16*)alloc(2ull * 128 * 192 * 2);
  u16* VRT     = (u16*)alloc(2ull * 192 * 128 * 2);
  u16* FCRT    = (u16*)alloc(6ull * 128 * 64 * 2);
  float* G   = (float*)alloc((2 * 3 * 4096 + 2) * 4);
  float* RE  = G + 2 * 3 * 4096;

  // aliases (lifetimes disjoint):
  u32* BP   = (u32*)HB;              // 28 MB; dead before hop L0
  u16* Z0   = HB;                    // [50000][192], fusion phase
  u16* Z1   = HB + 9600000ull;       // [80000][192]
  const int NP0 = 50016, NP1 = 80032;
  u16* ZT0  = (u16*)HISTA;           // 192*50016*2 = 19.2 MB <= CSR block 33.6 MB
  u16* ZT1  = TF;                    // 192*80032*2 = 30.7 MB <= 35.8 MB

  const int hbrow[7] = {0, 80000, 160000, 170000, 220000, 230000, 280000};
  auto HBp = [&](int c) { return HB + (size_t)hbrow[c] * 128; };
  auto RP  = [&](int g) { return ROWPTR14 + (size_t)g * RP_STRIDE; };
  auto ES  = [&](int g) { return ESRC14 + (size_t)g * E_EDGES; };
  auto BT  = [&](int et) { return BT_HOP + (size_t)et * 128 * 128; };
  auto BG  = [&](int et) { return b_gcn + (size_t)GRP_H[et] * 128; };

  // ---- batched weight transposes (24 jobs) --------------------------------
  TBatch tb;
  int tj = 0;
  for (int t = 0; t < 3; ++t)
    tb.j[tj++] = {W_type + (size_t)t * 256 * 128, WT_TYPE + (size_t)t * 128 * 256, nullptr, 256, 128};
  for (int et = 0; et < 5; ++et)
    tb.j[tj++] = {W_gcn + (size_t)GRP_H[et] * 128 * 128, BT_HOP + (size_t)et * 128 * 128,
                  comp + (size_t)et * 128, 128, 128};
  for (int L = 0; L < 2; ++L)
    for (int p = 0; p < 3; ++p)
      tb.j[tj++] = {fc[L] + (size_t)p * 128 * 64, FCT + (size_t)(L * 3 + p) * 64 * 128, nullptr, 128, 64};
  for (int L = 0; L < 2; ++L)
    for (int p = 0; p < 3; ++p)
      tb.j[tj++] = {fcr[L] + (size_t)p * 64 * 128, FCRT + (size_t)(L * 3 + p) * 128 * 64, nullptr, 64, 128};
  for (int L = 0; L < 2; ++L)
    tb.j[tj++] = {V[L], VT + (size_t)L * 128 * 192, nullptr, 192, 128};
  for (int L = 0; L < 2; ++L)
    tb.j[tj++] = {Vr[L], VRT + (size_t)L * 192 * 128, nullptr, 128, 192};
  transpose_b_k<<<dim3(128, 24), 256, 0, stream>>>(tb);

  // ---- inverse perms -------------------------------------------------------
  IBatch ib;
  ib.perm[0] = perm_u; ib.ip[0] = IPERM;          ib.n[0] = 50000;
  ib.perm[1] = perm_i; ib.ip[1] = IPERM + 50000;  ib.n[1] = 80000;
  iperm_b_k<<<dim3(313, 2), 256, 0, stream>>>(ib);

  // ---- CSR build for all 14 hops (two-level bucket sort, no global atomics)
  CsrP cpp;
  for (int g = 0; g < 14; ++g) {
    cpp.n[g] = HOPN[g];
    cpp.sh[g] = (HOPN[g] <= 10000) ? 6 : 8;
    cpp.P[g] = (HOPN[g] + (1 << cpp.sh[g]) - 1) >> cpp.sh[g];
  }
  csr_hist_k<<<dim3(NCH, 14), 256, 0, stream>>>(e_user, e_item, HISTA, cpp);
  csr_scan_k<<<dim3(14), 256, 0, stream>>>(HISTA, cpp);
  csr_scatter_k<<<dim3(NCH, 14), 256, 0, stream>>>(e_user, e_item, HISTA, BP, cpp);
  csr_fine_k<<<dim3(313, 14), 256, 0, stream>>>(BP, HISTA, ROWPTR14, ESRC14, cpp);
  hipMemsetAsync(G, 0, (2 * 3 * 4096 + 2) * 4, stream);

  // ---- NodeTransform (batched, 3 types) -----------------------------------
  {
    GemmBatch nb = {};
    for (int t = 0; t < 3; ++t)
      nb.j[t] = {features + (size_t)OFFS_H[t] * 256, WT_TYPE + (size_t)t * 128 * 256,
                 b_type + (size_t)t * 128, TF + (size_t)OFFS_H[t] * 128,
                 nullptr, COUNTS_H[t], 0};
    gemm_b_k<256, 128, ACT_RELU, 1, false, false>
        <<<dim3(1250, 3), 256, 0, stream>>>(nb, 256, 128);
  }

  // ---- hops in 4 dependency levels ----------------------------------------
  const u16* TF0 = TF;
  const u16* TF1 = TF + 50000ull * 128;
  const int* IPu = IPERM;
  const int* IPi = IPERM + 50000;

  HopBatch L0, L1, L2, L3;
  L0.j[0] = {TF0, RP(0),  ES(0),  BT(0), BG(0), HBp(0), nullptr, 80000, 0};
  L0.j[1] = {TF0, RP(2),  ES(2),  BT(0), BG(0), HBp(1), nullptr, 80000, 0};
  L0.j[2] = {TF0, RP(6),  ES(6),  BT(4), BG(4), OUTSu + 2ull * 50000 * 128, IPu, 50000, 1};
  L0.j[3] = {TF1, RP(7),  ES(7),  BT(1), BG(1), HBp(3), nullptr, 50000, 0};
  L0.j[4] = {TF1, RP(9),  ES(9),  BT(2), BG(2), HBp(4), nullptr, 10000, 0};
  L0.j[5] = {TF1, RP(11), ES(11), BT(1), BG(1), HBp(5), nullptr, 50000, 0};
  L1.j[0] = {HBp(0), RP(1),  ES(1),  BT(1), BG(1), OUTSu, IPu, 50000, 1};
  L1.j[1] = {HBp(1), RP(3),  ES(3),  BT(2), BG(2), HBp(2), nullptr, 10000, 0};
  L1.j[2] = {HBp(3), RP(8),  ES(8),  BT(0), BG(0), OUTSi, IPi, 80000, 1};
  L1.j[3] = {HBp(4), RP(10), ES(10), BT(3), BG(3), OUTSi + 1ull * 80000 * 128, IPi, 80000, 1};
  L1.j[4] = {HBp(5), RP(12), ES(12), BT(4), BG(4), HBp(6), nullptr, 50000, 0};
  L1.j[5] = L1.j[4];
  L2.j[0] = {HBp(2), RP(4),  ES(4),  BT(3), BG(3), HBp(0), nullptr, 80000, 0};
  L2.j[1] = {HBp(6), RP(13), ES(13), BT(0), BG(0), OUTSi + 2ull * 80000 * 128, IPi, 80000, 1};
  L2.j[2] = L2.j[1]; L2.j[3] = L2.j[1]; L2.j[4] = L2.j[1]; L2.j[5] = L2.j[1];
  L3.j[0] = {HBp(0), RP(5), ES(5), BT(1), BG(1), OUTSu + 1ull * 50000 * 128, IPu, 50000, 1};
  L3.j[1] = L3.j[0]; L3.j[2] = L3.j[0]; L3.j[3] = L3.j[0]; L3.j[4] = L3.j[0]; L3.j[5] = L3.j[0];

  hop_b_k<<<dim3(1250, 6), 256, 0, stream>>>(L0);
  hop_b_k<<<dim3(1250, 5), 256, 0, stream>>>(L1);
  hop_b_k<<<dim3(1250, 2), 256, 0, stream>>>(L2);
  hop_b_k<<<dim3(782, 1), 256, 0, stream>>>(L3);

  // ---- fusion (both layers batched) ---------------------------------------
  hipMemsetAsync(ZT0, 0, (size_t)192 * NP0 * 2, stream);
  hipMemsetAsync(ZT1, 0, (size_t)192 * NP1 * 2, stream);

  {
    GemmBatch fb = {};
    for (int p = 0; p < 3; ++p) {
      fb.j[p]     = {OUTSu + (size_t)p * 50000 * 128, FCT + (size_t)p * 64 * 128, nullptr,
                     Z0 + p * 64, ZT0 + (size_t)p * 64 * NP0, 50000, NP0};
      fb.j[p + 3] = {OUTSi + (size_t)p * 80000 * 128, FCT + (size_t)(3 + p) * 64 * 128, nullptr,
                     Z1 + p * 64, ZT1 + (size_t)p * 64 * NP1, 80000, NP1};
    }
    gemm_b_k<128, 64, ACT_TANH, 0, false, true>
        <<<dim3(1250, 6), 256, 0, stream>>>(fb, 128, 192);
  }

  gram_k<<<dim3(GRAM_NKB, 6), 256, 0, stream>>>(ZT0, ZT1, NP0, NP1, G);

  {
    VFJob j0 = {Z0, VT, VRT, FCRT, OUTSu, out, RE + 0, 50000};
    VFJob j1 = {Z1, VT + (size_t)128 * 192, VRT + (size_t)192 * 128, FCRT + (size_t)3 * 128 * 64,
                OUTSi, out + 6400000, RE + 1, 80000};
    vfuse_k<<<dim3(1250, 2), 256, 0, stream>>>(j0, j1);
  }

  loss_k<<<1, 256, 0, stream>>>(G, RE, out + 16640000);
}

// Round 16
// 1038.578 us; speedup vs baseline: 1.1181x; 1.0000x over previous
//
#include <hip/hip_runtime.h>

typedef unsigned short u16;
typedef unsigned int   u32;

#define ACT_NONE 0
#define ACT_RELU 1
#define ACT_TANH 2

#define E_EDGES 500000
#define RP_STRIDE 80004   // per-hop stride for rowptr (ints, 16B-aligned)
#define NCH 62            // edge chunks per hop (8192 edges each)
#define CH 8192
#define HSTRIDE 19456     // per-hop stride in HISTA (>= maxP(313)*NCH(62)=19406)

using s8vec = __attribute__((ext_vector_type(8))) short;   // 8 bf16 (4 VGPRs) MFMA A/B frag
using f4vec = __attribute__((ext_vector_type(4))) float;   // MFMA C/D frag

__device__ __forceinline__ float bf2f(u16 u) {
  union { u32 b; float f; } v; v.b = ((u32)u) << 16; return v.f;
}
__device__ __forceinline__ u16 f2bf(float x) {
  union { float f; u32 b; } v; v.f = x;
  u32 r = v.b + 0x7fffu + ((v.b >> 16) & 1u);   // round-to-nearest-even
  return (u16)(r >> 16);
}
__device__ __forceinline__ void acc8(float* acc, uint4 v) {
  union { u32 b; float f; } cv;
  cv.b = v.x << 16;         acc[0] += cv.f;
  cv.b = v.x & 0xffff0000u; acc[1] += cv.f;
  cv.b = v.y << 16;         acc[2] += cv.f;
  cv.b = v.y & 0xffff0000u; acc[3] += cv.f;
  cv.b = v.z << 16;         acc[4] += cv.f;
  cv.b = v.z & 0xffff0000u; acc[5] += cv.f;
  cv.b = v.w << 16;         acc[6] += cv.f;
  cv.b = v.w & 0xffff0000u; acc[7] += cv.f;
}

// ---------------------------------------------------------------------------
// batched transpose + cast f32->bf16 (+ optional per-row scale): in[R][C]->out[C][R]
struct TJob { const float* src; u16* dst; const float* scale; int R; int C; };
struct TBatch { TJob j[24]; };
__global__ __launch_bounds__(256) void transpose_b_k(TBatch b) {
  TJob jb = b.j[blockIdx.y];
  int i = blockIdx.x * 256 + threadIdx.x;
  if (i >= jb.R * jb.C) return;
  int r = i / jb.C, c = i % jb.C;
  float v = jb.src[i];
  if (jb.scale) v *= jb.scale[r];
  jb.dst[(size_t)c * jb.R + r] = f2bf(v);
}

// ---------------------------------------------------------------------------
// batched inverse permutation: ip[perm[i]] = i
struct IBatch { const int* perm[2]; int* ip[2]; int n[2]; };
__global__ __launch_bounds__(256) void iperm_b_k(IBatch b) {
  int y = blockIdx.y;
  int i = blockIdx.x * 256 + threadIdx.x;
  if (i < b.n[y]) b.ip[y][b.perm[y][i]] = i;
}

// ---------------------------------------------------------------------------
// Two-level bucket CSR build over 14 hops — ZERO global atomics.
struct CsrP { int n[14]; int sh[14]; int P[14]; };

__global__ __launch_bounds__(256) void csr_hist_k(
    const int* __restrict__ eu, const int* __restrict__ ei,
    int* __restrict__ hista, CsrP cp) {
  const int hop = blockIdx.y, chunk = blockIdx.x;
  const int P = cp.P[hop], sh = cp.sh[hop];
  __shared__ int hist[320];
  for (int i = threadIdx.x; i < P; i += 256) hist[i] = 0;
  __syncthreads();
  const int* edges = (hop < 7) ? eu : ei;
  const int h7 = (hop < 7) ? hop : hop - 7;
  const int* dstp = edges + (size_t)(h7 * 2 + 1) * E_EDGES;
  const int e0 = chunk * CH;
  const int e1 = min(E_EDGES, e0 + CH);
  for (int e = e0 + threadIdx.x * 4; e < e1; e += 1024) {
    int4 d4 = *(const int4*)(dstp + e);
    atomicAdd(&hist[d4.x >> sh], 1);
    atomicAdd(&hist[d4.y >> sh], 1);
    atomicAdd(&hist[d4.z >> sh], 1);
    atomicAdd(&hist[d4.w >> sh], 1);
  }
  __syncthreads();
  for (int i = threadIdx.x; i < P; i += 256)
    hista[(size_t)hop * HSTRIDE + i * NCH + chunk] = hist[i];
}

__global__ __launch_bounds__(256) void csr_scan_k(int* __restrict__ hista, CsrP cp) {
  const int hop = blockIdx.x;
  const int L = cp.P[hop] * NCH;
  int* a = hista + (size_t)hop * HSTRIDE;
  const int per = (L + 255) >> 8;
  const int lo = threadIdx.x * per;
  const int hi = min(L, lo + per);
  int s = 0;
  for (int i = lo; i < hi; ++i) s += a[i];
  __shared__ int lds[256];
  lds[threadIdx.x] = s;
  __syncthreads();
  for (int off = 1; off < 256; off <<= 1) {
    int v = (threadIdx.x >= off) ? lds[threadIdx.x - off] : 0;
    __syncthreads();
    lds[threadIdx.x] += v;
    __syncthreads();
  }
  int run = threadIdx.x ? lds[threadIdx.x - 1] : 0;
  for (int i = lo; i < hi; ++i) { int v = a[i]; a[i] = run; run += v; }
}

__global__ __launch_bounds__(256) void csr_scatter_k(
    const int* __restrict__ eu, const int* __restrict__ ei,
    const int* __restrict__ hista, u32* __restrict__ bp, CsrP cp) {
  const int hop = blockIdx.y, chunk = blockIdx.x;
  const int P = cp.P[hop], sh = cp.sh[hop];
  const u32 fm = (1u << sh) - 1u;
  __shared__ int cur[320];
  for (int i = threadIdx.x; i < P; i += 256)
    cur[i] = hista[(size_t)hop * HSTRIDE + i * NCH + chunk];
  __syncthreads();
  const int* edges = (hop < 7) ? eu : ei;
  const int h7 = (hop < 7) ? hop : hop - 7;
  const int* srcp = edges + (size_t)(h7 * 2) * E_EDGES;
  const int* dstp = srcp + E_EDGES;
  u32* b = bp + (size_t)hop * E_EDGES;
  const int e0 = chunk * CH;
  const int e1 = min(E_EDGES, e0 + CH);
  for (int e = e0 + threadIdx.x * 4; e < e1; e += 1024) {
    int4 d4 = *(const int4*)(dstp + e);
    int4 s4 = *(const int4*)(srcp + e);
    int dd[4] = {d4.x, d4.y, d4.z, d4.w};
    int ss[4] = {s4.x, s4.y, s4.z, s4.w};
#pragma unroll
    for (int j = 0; j < 4; ++j) {
      int pos = atomicAdd(&cur[dd[j] >> sh], 1);   // LDS atomic
      b[pos] = (u32)ss[j] | (((u32)dd[j] & fm) << 24);
    }
  }
}

__global__ __launch_bounds__(256) void csr_fine_k(
    const u32* __restrict__ bp, const int* __restrict__ hista,
    int* __restrict__ rowptrb, int* __restrict__ esrcb, CsrP cp) {
  const int hop = blockIdx.y, p = blockIdx.x;
  const int P = cp.P[hop];
  if (p >= P) return;
  const int n = cp.n[hop], sh = cp.sh[hop], W = 1 << sh;
  const int* fl = hista + (size_t)hop * HSTRIDE;
  const int beg = fl[p * NCH];
  const int end = (p + 1 < P) ? fl[(p + 1) * NCH] : E_EDGES;
  const int nb = min(W, n - p * W);
  const int tid = threadIdx.x;

  __shared__ int fh[256];
  __shared__ int sc[256];
  __shared__ int cur[256];
  fh[tid] = 0;
  __syncthreads();
  const u32* b = bp + (size_t)hop * E_EDGES;
  for (int i = beg + tid; i < end; i += 256)
    atomicAdd(&fh[b[i] >> 24], 1);
  __syncthreads();
  sc[tid] = fh[tid];
  __syncthreads();
  for (int off = 1; off < 256; off <<= 1) {
    int v = (tid >= off) ? sc[tid - off] : 0;
    __syncthreads();
    sc[tid] += v;
    __syncthreads();
  }
  const int excl = tid ? sc[tid - 1] : 0;
  int* rowptr = rowptrb + (size_t)hop * RP_STRIDE;
  if (tid < nb) rowptr[p * W + tid] = beg + excl;
  cur[tid] = beg + excl;
  if (p == P - 1 && tid == 0) rowptr[n] = E_EDGES;
  __syncthreads();
  int* esrc = esrcb + (size_t)hop * E_EDGES;
  for (int i = beg + tid; i < end; i += 256) {
    u32 v = b[i];
    int pos = atomicAdd(&cur[v >> 24], 1);        // LDS atomic
    esrc[pos] = (int)(v & 0xFFFFFFu);
  }
}

// ---------------------------------------------------------------------------
// Level-batched fused hop kernel (R10 config: LDS B-tile, 2-deep gather)
struct HopJob {
  const u16* h; const int* rowptr; const int* esrc;
  const u16* Bt; const float* bias; u16* out;
  const int* iperm; int n; int permout;
};
struct HopBatch { HopJob j[6]; };

__global__ __launch_bounds__(256) void hop_b_k(HopBatch batch) {
  const HopJob jb = batch.j[blockIdx.y];
  const int rbase = blockIdx.x * 64;
  if (rbase >= jb.n) return;

  __shared__ u16 bts[128 * 128];
  const int tid = threadIdx.x;
  // stage Bt[128][128] -> LDS with 16B-granule XOR swizzle
  for (int i = tid; i < 128 * 16; i += 256) {
    int nn = i >> 4, g = i & 15;
    int gs = (g & 8) | ((g ^ nn) & 7);
    *(uint4*)(&bts[nn * 128 + gs * 8]) = *(const uint4*)(jb.Bt + (size_t)nn * 128 + g * 8);
  }
  __syncthreads();

  const int wave = tid >> 6;
  const int lane = tid & 63;
  const int kgrp = lane >> 4;
  const int lid  = lane & 15;
  const int d = rbase + wave * 16 + lid;

  float a0[8] = {0,0,0,0,0,0,0,0}, a1[8] = {0,0,0,0,0,0,0,0};
  float a2[8] = {0,0,0,0,0,0,0,0}, a3[8] = {0,0,0,0,0,0,0,0};
  int s0 = 0, s1 = 0;
  if (d < jb.n) { s0 = jb.rowptr[d]; s1 = jb.rowptr[d + 1]; }
  const u16* hk = jb.h + kgrp * 8;
  int i = s0;
  for (; i + 1 < s1; i += 2) {
    const u16* ra = hk + (size_t)jb.esrc[i] * 128;
    const u16* rb = hk + (size_t)jb.esrc[i + 1] * 128;
    uint4 va0 = *(const uint4*)(ra);      uint4 vb0 = *(const uint4*)(rb);
    uint4 va1 = *(const uint4*)(ra + 32); uint4 vb1 = *(const uint4*)(rb + 32);
    uint4 va2 = *(const uint4*)(ra + 64); uint4 vb2 = *(const uint4*)(rb + 64);
    uint4 va3 = *(const uint4*)(ra + 96); uint4 vb3 = *(const uint4*)(rb + 96);
    acc8(a0, va0); acc8(a1, va1); acc8(a2, va2); acc8(a3, va3);
    acc8(a0, vb0); acc8(a1, vb1); acc8(a2, vb2); acc8(a3, vb3);
  }
  if (i < s1) {
    const u16* ra = hk + (size_t)jb.esrc[i] * 128;
    acc8(a0, *(const uint4*)(ra));
    acc8(a1, *(const uint4*)(ra + 32));
    acc8(a2, *(const uint4*)(ra + 64));
    acc8(a3, *(const uint4*)(ra + 96));
  }
  const float rs = 1.0f / fmaxf((float)(s1 - s0), 1.0f);
  s8vec f0, f1, f2, f3;
#pragma unroll
  for (int j = 0; j < 8; ++j) f0[j] = (short)f2bf(a0[j] * rs);
#pragma unroll
  for (int j = 0; j < 8; ++j) f1[j] = (short)f2bf(a1[j] * rs);
#pragma unroll
  for (int j = 0; j < 8; ++j) f2[j] = (short)f2bf(a2[j] * rs);
#pragma unroll
  for (int j = 0; j < 8; ++j) f3[j] = (short)f2bf(a3[j] * rs);

  int rout[4];
#pragma unroll
  for (int j = 0; j < 4; ++j) {
    int rv = rbase + wave * 16 + kgrp * 4 + j;
    rout[j] = (rv < jb.n) ? (jb.permout ? jb.iperm[rv] : rv) : -1;
  }

#pragma unroll
  for (int t = 0; t < 8; ++t) {
    f4vec c = {0.f, 0.f, 0.f, 0.f};
    const int bn = t * 16 + lid;
    int g = kgrp;
    int gs = (g & 8) | ((g ^ bn) & 7);
    c = __builtin_amdgcn_mfma_f32_16x16x32_bf16(f0, *(const s8vec*)(&bts[bn * 128 + gs * 8]), c, 0, 0, 0);
    g = 4 + kgrp; gs = (g & 8) | ((g ^ bn) & 7);
    c = __builtin_amdgcn_mfma_f32_16x16x32_bf16(f1, *(const s8vec*)(&bts[bn * 128 + gs * 8]), c, 0, 0, 0);
    g = 8 + kgrp; gs = (g & 8) | ((g ^ bn) & 7);
    c = __builtin_amdgcn_mfma_f32_16x16x32_bf16(f2, *(const s8vec*)(&bts[bn * 128 + gs * 8]), c, 0, 0, 0);
    g = 12 + kgrp; gs = (g & 8) | ((g ^ bn) & 7);
    c = __builtin_amdgcn_mfma_f32_16x16x32_bf16(f3, *(const s8vec*)(&bts[bn * 128 + gs * 8]), c, 0, 0, 0);
    const float bb = jb.bias[bn];
#pragma unroll
    for (int j = 0; j < 4; ++j) {
      if (rout[j] >= 0) {
        float v = c[j] + bb;
        jb.out[(size_t)rout[j] * 128 + bn] = f2bf(v);
      }
    }
  }
}

// ---------------------------------------------------------------------------
// Batched MFMA GEMM: C[M][N] = act(A[M][K] @ B[K][N] + bias); Bt=[N][K] bf16.
struct GemmJob {
  const void* A; const u16* Bt; const float* bias; void* C;
  u16* Ct; int M; int ldCt;
};
struct GemmBatch { GemmJob j[6]; };

template <int K, int N, int ACT, int AMODE, bool CF32, bool CTR>
__global__ __launch_bounds__(256) void gemm_b_k(
    GemmBatch batch, int ldA, int ldC) {
  static_assert(K % 32 == 0 && N % 16 == 0, "");
  const GemmJob jb = batch.j[blockIdx.y];
  const int rbase0 = blockIdx.x * 64;
  if (rbase0 >= jb.M) return;

  __shared__ u16 bts[N * K];

  const int tid = threadIdx.x;
  for (int i = tid; i < N * (K / 8); i += 256) {
    int n = i / (K / 8);
    int g = i % (K / 8);
    int gs = (g & ~7) | ((g ^ n) & 7);
    *(uint4*)(&bts[n * K + gs * 8]) = *(const uint4*)(jb.Bt + (size_t)n * K + g * 8);
  }
  __syncthreads();

  const int wave = tid >> 6;
  const int lane = tid & 63;
  const int kgrp = lane >> 4;
  const int rbase = rbase0 + wave * 16;
  const int rowA = rbase + (lane & 15);
  const bool av = rowA < jb.M;

  s8vec afr[K / 32];
  if constexpr (AMODE == 1) {
    const float* arow = (const float*)jb.A + (size_t)rowA * ldA;
#pragma unroll
    for (int kt = 0; kt < K / 32; ++kt) {
      s8vec fr = {0, 0, 0, 0, 0, 0, 0, 0};
      if (av) {
        const float* p = arow + kt * 32 + kgrp * 8;
        float4 fa = *(const float4*)(p);
        float4 fb = *(const float4*)(p + 4);
        fr[0] = (short)f2bf(fa.x); fr[1] = (short)f2bf(fa.y);
        fr[2] = (short)f2bf(fa.z); fr[3] = (short)f2bf(fa.w);
        fr[4] = (short)f2bf(fb.x); fr[5] = (short)f2bf(fb.y);
        fr[6] = (short)f2bf(fb.z); fr[7] = (short)f2bf(fb.w);
      }
      afr[kt] = fr;
    }
  } else {
    const u16* arow = (const u16*)jb.A + (size_t)rowA * ldA;
#pragma unroll
    for (int kt = 0; kt < K / 32; ++kt) {
      s8vec fr = {0, 0, 0, 0, 0, 0, 0, 0};
      if (av) fr = *(const s8vec*)(arow + kt * 32 + kgrp * 8);
      afr[kt] = fr;
    }
  }

#pragma unroll
  for (int t = 0; t < N / 16; ++t) {
    f4vec acc = {0.f, 0.f, 0.f, 0.f};
    const int bn = t * 16 + (lane & 15);
#pragma unroll
    for (int kt = 0; kt < K / 32; ++kt) {
      int g = kt * 4 + kgrp;
      int gs = (g & ~7) | ((g ^ bn) & 7);
      s8vec bfr = *(const s8vec*)(&bts[bn * K + gs * 8]);
      acc = __builtin_amdgcn_mfma_f32_16x16x32_bf16(afr[kt], bfr, acc, 0, 0, 0);
    }
    const int col = t * 16 + (lane & 15);
    float bb = jb.bias ? jb.bias[col] : 0.0f;
#pragma unroll
    for (int j = 0; j < 4; ++j) {
      int r = rbase + kgrp * 4 + j;        // C/D: col=lane&15, row=(lane>>4)*4+j
      if (r < jb.M) {
        float v = acc[j] + bb;
        if constexpr (ACT == ACT_RELU) v = fmaxf(v, 0.0f);
        if constexpr (ACT == ACT_TANH) v = tanhf(v);
        if constexpr (CF32) {
          ((float*)jb.C)[(size_t)r * ldC + col] = v;
        } else {
          ((u16*)jb.C)[(size_t)r * ldC + col] = f2bf(v);
        }
        if constexpr (CTR) {
          jb.Ct[(size_t)col * jb.ldCt + r] = f2bf(v);
        }
      }
    }
  }
}

// ---------------------------------------------------------------------------
// Fused V -> Vr -> fcr+sqdiff (3-stage, per layer). v3: t-QUAD register tiling
// — all B-fragments for 4 output tiles loaded into registers up front (24
// s8vec live in stage 1), 4 independent MFMA chains interleaved over kt.
struct VFJob {
  const u16* Z;      // [M][192]
  const u16* VT;     // [128][192]  (Bt stage1)
  const u16* VRT;    // [192][128]  (Bt stage2)
  const u16* FCRT;   // 3 x [128][64] (Bt stage3)
  const u16* target; // OUTS_L: 3 x [M][128]
  float* fused;      // [M][128] f32 (model output)
  float* loss;       // RE + L
  int M;
};

__global__ __launch_bounds__(256, 3) void vfuse_k(VFJob j0, VFJob j1) {
  const VFJob jb = blockIdx.y ? j1 : j0;
  const int rbase = blockIdx.x * 64;
  if (rbase >= jb.M) return;

  __shared__ u16 ftile[64 * 128];   // fused tile, bf16, granule-swizzled
  __shared__ u16 ztile[64 * 192];   // zrec tile, bf16, granule-swizzled
  __shared__ float red[4];

  const int tid = threadIdx.x;
  const int wave = tid >> 6;
  const int lane = tid & 63;
  const int kgrp = lane >> 4;
  const int lid  = lane & 15;
  const int arow_l = wave * 16 + lid;       // LDS-local A row for stages 2,3
  const int rowA = rbase + arow_l;
  const bool av = rowA < jb.M;

  // ---- stage 1: fused = Z @ V  (K=192, N=128), 2 t-quads ----
  s8vec az[6];
#pragma unroll
  for (int kt = 0; kt < 6; ++kt) {
    s8vec fr = {0, 0, 0, 0, 0, 0, 0, 0};
    if (av) fr = *(const s8vec*)(jb.Z + (size_t)rowA * 192 + kt * 32 + kgrp * 8);
    az[kt] = fr;
  }
#pragma unroll
  for (int tq = 0; tq < 2; ++tq) {
    s8vec bf[4][6];
#pragma unroll
    for (int h = 0; h < 4; ++h) {
      const int bn = (tq * 4 + h) * 16 + lid;
      const u16* brow = jb.VT + (size_t)bn * 192 + kgrp * 8;
#pragma unroll
      for (int kt = 0; kt < 6; ++kt) bf[h][kt] = *(const s8vec*)(brow + kt * 32);
    }
    f4vec c[4] = {{0.f,0.f,0.f,0.f},{0.f,0.f,0.f,0.f},{0.f,0.f,0.f,0.f},{0.f,0.f,0.f,0.f}};
#pragma unroll
    for (int kt = 0; kt < 6; ++kt)
#pragma unroll
      for (int h = 0; h < 4; ++h)
        c[h] = __builtin_amdgcn_mfma_f32_16x16x32_bf16(az[kt], bf[h][kt], c[h], 0, 0, 0);
#pragma unroll
    for (int h = 0; h < 4; ++h) {
      const int bn = (tq * 4 + h) * 16 + lid;
      const int g = bn >> 3;
#pragma unroll
      for (int j = 0; j < 4; ++j) {
        int rl = wave * 16 + kgrp * 4 + j;
        int r = rbase + rl;
        int gs = (g & 8) | ((g ^ rl) & 7);
        if (r < jb.M) {
          jb.fused[(size_t)r * 128 + bn] = c[h][j];
          ftile[rl * 128 + gs * 8 + (bn & 7)] = f2bf(c[h][j]);
        } else {
          ftile[rl * 128 + gs * 8 + (bn & 7)] = 0;
        }
      }
    }
  }
  __syncthreads();

  // ---- stage 2: zrec = fused @ Vr  (K=128, N=192), 3 t-quads ----
  s8vec af[4];
#pragma unroll
  for (int kt = 0; kt < 4; ++kt) {
    int ga = kt * 4 + kgrp;
    int gs = (ga & 8) | ((ga ^ arow_l) & 7);
    af[kt] = *(const s8vec*)(&ftile[arow_l * 128 + gs * 8]);
  }
#pragma unroll
  for (int tq = 0; tq < 3; ++tq) {
    s8vec bf[4][4];
#pragma unroll
    for (int h = 0; h < 4; ++h) {
      const int bn = (tq * 4 + h) * 16 + lid;
      const u16* brow = jb.VRT + (size_t)bn * 128 + kgrp * 8;
#pragma unroll
      for (int kt = 0; kt < 4; ++kt) bf[h][kt] = *(const s8vec*)(brow + kt * 32);
    }
    f4vec c[4] = {{0.f,0.f,0.f,0.f},{0.f,0.f,0.f,0.f},{0.f,0.f,0.f,0.f},{0.f,0.f,0.f,0.f}};
#pragma unroll
    for (int kt = 0; kt < 4; ++kt)
#pragma unroll
      for (int h = 0; h < 4; ++h)
        c[h] = __builtin_amdgcn_mfma_f32_16x16x32_bf16(af[kt], bf[h][kt], c[h], 0, 0, 0);
#pragma unroll
    for (int h = 0; h < 4; ++h) {
      const int bn = (tq * 4 + h) * 16 + lid;
      const int g = bn >> 3;
#pragma unroll
      for (int j = 0; j < 4; ++j) {
        int rl = wave * 16 + kgrp * 4 + j;
        int gs = (g & ~7) | ((g ^ rl) & 7);
        ztile[rl * 192 + gs * 8 + (bn & 7)] = f2bf(c[h][j]);
      }
    }
  }
  __syncthreads();

  // ---- stage 3: per p, h_rec = zrec[:,p] @ fcr[p]  (K=64, N=128), 2 t-quads,
  //      sqdiff vs target ----
  float sqsum = 0.0f;
#pragma unroll
  for (int p = 0; p < 3; ++p) {
    s8vec aq[2];
#pragma unroll
    for (int kt = 0; kt < 2; ++kt) {
      int ga = p * 8 + kt * 4 + kgrp;
      int gs = (ga & ~7) | ((ga ^ arow_l) & 7);
      aq[kt] = *(const s8vec*)(&ztile[arow_l * 192 + gs * 8]);
    }
    const u16* fp = jb.FCRT + (size_t)p * 128 * 64;
    const u16* tgt = jb.target + (size_t)p * jb.M * 128;
#pragma unroll
    for (int tq = 0; tq < 2; ++tq) {
      s8vec bf[4][2];
#pragma unroll
      for (int h = 0; h < 4; ++h) {
        const int bn = (tq * 4 + h) * 16 + lid;
        const u16* brow = fp + (size_t)bn * 64 + kgrp * 8;
        bf[h][0] = *(const s8vec*)(brow);
        bf[h][1] = *(const s8vec*)(brow + 32);
      }
      f4vec c[4] = {{0.f,0.f,0.f,0.f},{0.f,0.f,0.f,0.f},{0.f,0.f,0.f,0.f},{0.f,0.f,0.f,0.f}};
#pragma unroll
      for (int kt = 0; kt < 2; ++kt)
#pragma unroll
        for (int h = 0; h < 4; ++h)
          c[h] = __builtin_amdgcn_mfma_f32_16x16x32_bf16(aq[kt], bf[h][kt], c[h], 0, 0, 0);
#pragma unroll
      for (int h = 0; h < 4; ++h) {
        const int bn = (tq * 4 + h) * 16 + lid;
#pragma unroll
        for (int j = 0; j < 4; ++j) {
          int r = rbase + wave * 16 + kgrp * 4 + j;
          if (r < jb.M) {
            float dd = c[h][j] - bf2f(tgt[(size_t)r * 128 + bn]);
            sqsum += dd * dd;
          }
        }
      }
    }
  }
#pragma unroll
  for (int off = 32; off > 0; off >>= 1) sqsum += __shfl_down(sqsum, off);
  if (lane == 0) red[wave] = sqsum;
  __syncthreads();
  if (tid == 0) atomicAdd(jb.loss, red[0] + red[1] + red[2] + red[3]);
}

// ---------------------------------------------------------------------------
// Gram via MFMA, both layers: y = layer*3 + pair
#define GRAM_NKB 40
__global__ __launch_bounds__(256) void gram_k(
    const u16* __restrict__ zt0, const u16* __restrict__ zt1,
    int NP0, int NP1, float* __restrict__ G) {
  const int layer = blockIdx.y / 3;
  const int pair = blockIdx.y % 3;
  const u16* zt = layer ? zt1 : zt0;
  const int NP = layer ? NP1 : NP0;
  const int p = (pair == 2) ? 1 : 0;
  const int q = (pair == 0) ? 1 : 2;
  const int wave = threadIdx.x >> 6;
  const int lane = threadIdx.x & 63;
  const int kgrp = lane >> 4, lid = lane & 15;

  const int KC = (((NP + GRAM_NKB - 1) / GRAM_NKB) + 31) & ~31;
  const int kbeg = blockIdx.x * KC;
  const int kend = min(NP, kbeg + KC);

  const u16* arow = zt + (size_t)(p * 64 + wave * 16 + lid) * NP;
  const u16* brow0 = zt + (size_t)(q * 64 + 0 * 16 + lid) * NP;
  const u16* brow1 = zt + (size_t)(q * 64 + 1 * 16 + lid) * NP;
  const u16* brow2 = zt + (size_t)(q * 64 + 2 * 16 + lid) * NP;
  const u16* brow3 = zt + (size_t)(q * 64 + 3 * 16 + lid) * NP;

  f4vec acc0 = {0.f, 0.f, 0.f, 0.f};
  f4vec acc1 = {0.f, 0.f, 0.f, 0.f};
  f4vec acc2 = {0.f, 0.f, 0.f, 0.f};
  f4vec acc3 = {0.f, 0.f, 0.f, 0.f};

  for (int k0 = kbeg; k0 < kend; k0 += 32) {
    const int ko = k0 + kgrp * 8;
    s8vec af = *(const s8vec*)(arow + ko);
    s8vec b0 = *(const s8vec*)(brow0 + ko);
    s8vec b1 = *(const s8vec*)(brow1 + ko);
    s8vec b2 = *(const s8vec*)(brow2 + ko);
    s8vec b3 = *(const s8vec*)(brow3 + ko);
    acc0 = __builtin_amdgcn_mfma_f32_16x16x32_bf16(af, b0, acc0, 0, 0, 0);
    acc1 = __builtin_amdgcn_mfma_f32_16x16x32_bf16(af, b1, acc1, 0, 0, 0);
    acc2 = __builtin_amdgcn_mfma_f32_16x16x32_bf16(af, b2, acc2, 0, 0, 0);
    acc3 = __builtin_amdgcn_mfma_f32_16x16x32_bf16(af, b3, acc3, 0, 0, 0);
  }

  float* g = G + (size_t)layer * 3 * 4096 + (size_t)pair * 4096;
  const int mrow = wave * 16 + kgrp * 4;
#pragma unroll
  for (int j = 0; j < 4; ++j) {
    atomicAdd(&g[(mrow + j) * 64 + 0 * 16 + lid], acc0[j]);
    atomicAdd(&g[(mrow + j) * 64 + 1 * 16 + lid], acc1[j]);
    atomicAdd(&g[(mrow + j) * 64 + 2 * 16 + lid], acc2[j]);
    atomicAdd(&g[(mrow + j) * 64 + 3 * 16 + lid], acc3[j]);
  }
}

// ---------------------------------------------------------------------------
__global__ __launch_bounds__(256) void loss_k(
    const float* __restrict__ G, const float* __restrict__ RE,
    float* __restrict__ out) {
  float s = 0.f;
  for (int i = threadIdx.x; i < 2 * 3 * 4096; i += 256) { float g = G[i]; s += g * g; }
#pragma unroll
  for (int off = 32; off > 0; off >>= 1) s += __shfl_down(s, off);
  __shared__ float red[4];
  int wave = threadIdx.x >> 6, lane = threadIdx.x & 63;
  if (lane == 0) red[wave] = s;
  __syncthreads();
  if (threadIdx.x == 0) {
    float orth = (red[0] + red[1] + red[2] + red[3]) / 4096.0f;
    float loss = orth + RE[0] / (50000.0f * 128.0f) + RE[1] / (80000.0f * 128.0f);
    out[0] = loss;
  }
}

// ---------------------------------------------------------------------------
static const int COUNTS_H[3] = {50000, 80000, 10000};
static const int OFFS_H[3]   = {0, 50000, 130000};
static const int GRP_H[5]    = {2, 1, 1, 2, 1};                // GCN_GROUP
static const int HOPN[14] = {80000, 50000, 80000, 10000, 80000, 50000, 50000,
                             50000, 80000, 10000, 80000, 50000, 50000, 80000};

extern "C" void kernel_launch(void* const* d_in, const int* in_sizes, int n_in,
                              void* d_out, int out_size, void* d_ws, size_t ws_size,
                              hipStream_t stream) {
  (void)in_sizes; (void)n_in; (void)out_size; (void)ws_size;

  const float* features = (const float*)d_in[0];
  const int* e_user   = (const int*)d_in[1];
  const int* e_item   = (const int*)d_in[2];
  const int* perm_u   = (const int*)d_in[3];
  const int* perm_i   = (const int*)d_in[4];
  const float* W_type = (const float*)d_in[5];
  const float* b_type = (const float*)d_in[6];
  const float* comp   = (const float*)d_in[7];
  const float* W_gcn  = (const float*)d_in[8];
  const float* b_gcn  = (const float*)d_in[9];
  const float* fc[2]  = {(const float*)d_in[10], (const float*)d_in[14]};
  const float* fcr[2] = {(const float*)d_in[11], (const float*)d_in[15]};
  const float* V[2]   = {(const float*)d_in[12], (const float*)d_in[16]};
  const float* Vr[2]  = {(const float*)d_in[13], (const float*)d_in[17]};
  float* out = (float*)d_out;

  char* base = (char*)d_ws;
  size_t off = 0;
  auto alloc = [&](size_t b) -> void* {
    void* p = base + off;
    off = (off + b + 255) & ~(size_t)255;
    return p;
  };
  u16* TF    = (u16*)alloc(140000ull * 128 * 2);      // ZT1 aliases (30.7 <= 35.8 MB)
  u16* HB    = (u16*)alloc(330000ull * 128 * 2);      // chain bufs; BP early; Z0/Z1 late
  u16* OUTSu = (u16*)alloc(3ull * 50000 * 128 * 2);
  u16* OUTSi = (u16*)alloc(3ull * 80000 * 128 * 2);
  int* HISTA    = (int*)alloc(14ull * HSTRIDE * 4);   // ZT0 aliases from here
  int* ROWPTR14 = (int*)alloc(14ull * RP_STRIDE * 4);
  int* ESRC14   = (int*)alloc(14ull * E_EDGES * 4);
  int* IPERM    = (int*)alloc(130000ull * 4);         // [user 50k][item 80k]
  u16* WT_TYPE = (u16*)alloc(3ull * 128 * 256 * 2);
  u16* BT_HOP  = (u16*)alloc(5ull * 128 * 128 * 2);
  u16* FCT     = (u16*)alloc(6ull * 64 * 128 * 2);
  u16* VT      = (u16*)alloc(2ull * 128 * 192 * 2);
  u16* VRT     = (u16*)alloc(2ull * 192 * 128 * 2);
  u16* FCRT    = (u16*)alloc(6ull * 128 * 64 * 2);
  float* G   = (float*)alloc((2 * 3 * 4096 + 2) * 4);
  float* RE  = G + 2 * 3 * 4096;

  // aliases (lifetimes disjoint):
  u32* BP   = (u32*)HB;              // 28 MB; dead before hop L0
  u16* Z0   = HB;                    // [50000][192], fusion phase
  u16* Z1   = HB + 9600000ull;       // [80000][192]
  const int NP0 = 50016, NP1 = 80032;
  u16* ZT0  = (u16*)HISTA;           // 192*50016*2 = 19.2 MB <= CSR block 33.6 MB
  u16* ZT1  = TF;                    // 192*80032*2 = 30.7 MB <= 35.8 MB

  const int hbrow[7] = {0, 80000, 160000, 170000, 220000, 230000, 280000};
  auto HBp = [&](int c) { return HB + (size_t)hbrow[c] * 128; };
  auto RP  = [&](int g) { return ROWPTR14 + (size_t)g * RP_STRIDE; };
  auto ES  = [&](int g) { return ESRC14 + (size_t)g * E_EDGES; };
  auto BT  = [&](int et) { return BT_HOP + (size_t)et * 128 * 128; };
  auto BG  = [&](int et) { return b_gcn + (size_t)GRP_H[et] * 128; };

  // ---- batched weight transposes (24 jobs) --------------------------------
  TBatch tb;
  int tj = 0;
  for (int t = 0; t < 3; ++t)
    tb.j[tj++] = {W_type + (size_t)t * 256 * 128, WT_TYPE + (size_t)t * 128 * 256, nullptr, 256, 128};
  for (int et = 0; et < 5; ++et)
    tb.j[tj++] = {W_gcn + (size_t)GRP_H[et] * 128 * 128, BT_HOP + (size_t)et * 128 * 128,
                  comp + (size_t)et * 128, 128, 128};
  for (int L = 0; L < 2; ++L)
    for (int p = 0; p < 3; ++p)
      tb.j[tj++] = {fc[L] + (size_t)p * 128 * 64, FCT + (size_t)(L * 3 + p) * 64 * 128, nullptr, 128, 64};
  for (int L = 0; L < 2; ++L)
    for (int p = 0; p < 3; ++p)
      tb.j[tj++] = {fcr[L] + (size_t)p * 64 * 128, FCRT + (size_t)(L * 3 + p) * 128 * 64, nullptr, 64, 128};
  for (int L = 0; L < 2; ++L)
    tb.j[tj++] = {V[L], VT + (size_t)L * 128 * 192, nullptr, 192, 128};
  for (int L = 0; L < 2; ++L)
    tb.j[tj++] = {Vr[L], VRT + (size_t)L * 192 * 128, nullptr, 128, 192};
  transpose_b_k<<<dim3(128, 24), 256, 0, stream>>>(tb);

  // ---- inverse perms -------------------------------------------------------
  IBatch ib;
  ib.perm[0] = perm_u; ib.ip[0] = IPERM;          ib.n[0] = 50000;
  ib.perm[1] = perm_i; ib.ip[1] = IPERM + 50000;  ib.n[1] = 80000;
  iperm_b_k<<<dim3(313, 2), 256, 0, stream>>>(ib);

  // ---- CSR build for all 14 hops (two-level bucket sort, no global atomics)
  CsrP cpp;
  for (int g = 0; g < 14; ++g) {
    cpp.n[g] = HOPN[g];
    cpp.sh[g] = (HOPN[g] <= 10000) ? 6 : 8;
    cpp.P[g] = (HOPN[g] + (1 << cpp.sh[g]) - 1) >> cpp.sh[g];
  }
  csr_hist_k<<<dim3(NCH, 14), 256, 0, stream>>>(e_user, e_item, HISTA, cpp);
  csr_scan_k<<<dim3(14), 256, 0, stream>>>(HISTA, cpp);
  csr_scatter_k<<<dim3(NCH, 14), 256, 0, stream>>>(e_user, e_item, HISTA, BP, cpp);
  csr_fine_k<<<dim3(313, 14), 256, 0, stream>>>(BP, HISTA, ROWPTR14, ESRC14, cpp);
  hipMemsetAsync(G, 0, (2 * 3 * 4096 + 2) * 4, stream);

  // ---- NodeTransform (batched, 3 types) -----------------------------------
  {
    GemmBatch nb = {};
    for (int t = 0; t < 3; ++t)
      nb.j[t] = {features + (size_t)OFFS_H[t] * 256, WT_TYPE + (size_t)t * 128 * 256,
                 b_type + (size_t)t * 128, TF + (size_t)OFFS_H[t] * 128,
                 nullptr, COUNTS_H[t], 0};
    gemm_b_k<256, 128, ACT_RELU, 1, false, false>
        <<<dim3(1250, 3), 256, 0, stream>>>(nb, 256, 128);
  }

  // ---- hops in 4 dependency levels ----------------------------------------
  const u16* TF0 = TF;
  const u16* TF1 = TF + 50000ull * 128;
  const int* IPu = IPERM;
  const int* IPi = IPERM + 50000;

  HopBatch L0, L1, L2, L3;
  L0.j[0] = {TF0, RP(0),  ES(0),  BT(0), BG(0), HBp(0), nullptr, 80000, 0};
  L0.j[1] = {TF0, RP(2),  ES(2),  BT(0), BG(0), HBp(1), nullptr, 80000, 0};
  L0.j[2] = {TF0, RP(6),  ES(6),  BT(4), BG(4), OUTSu + 2ull * 50000 * 128, IPu, 50000, 1};
  L0.j[3] = {TF1, RP(7),  ES(7),  BT(1), BG(1), HBp(3), nullptr, 50000, 0};
  L0.j[4] = {TF1, RP(9),  ES(9),  BT(2), BG(2), HBp(4), nullptr, 10000, 0};
  L0.j[5] = {TF1, RP(11), ES(11), BT(1), BG(1), HBp(5), nullptr, 50000, 0};
  L1.j[0] = {HBp(0), RP(1),  ES(1),  BT(1), BG(1), OUTSu, IPu, 50000, 1};
  L1.j[1] = {HBp(1), RP(3),  ES(3),  BT(2), BG(2), HBp(2), nullptr, 10000, 0};
  L1.j[2] = {HBp(3), RP(8),  ES(8),  BT(0), BG(0), OUTSi, IPi, 80000, 1};
  L1.j[3] = {HBp(4), RP(10), ES(10), BT(3), BG(3), OUTSi + 1ull * 80000 * 128, IPi, 80000, 1};
  L1.j[4] = {HBp(5), RP(12), ES(12), BT(4), BG(4), HBp(6), nullptr, 50000, 0};
  L1.j[5] = L1.j[4];
  L2.j[0] = {HBp(2), RP(4),  ES(4),  BT(3), BG(3), HBp(0), nullptr, 80000, 0};
  L2.j[1] = {HBp(6), RP(13), ES(13), BT(0), BG(0), OUTSi + 2ull * 80000 * 128, IPi, 80000, 1};
  L2.j[2] = L2.j[1]; L2.j[3] = L2.j[1]; L2.j[4] = L2.j[1]; L2.j[5] = L2.j[1];
  L3.j[0] = {HBp(0), RP(5), ES(5), BT(1), BG(1), OUTSu + 1ull * 50000 * 128, IPu, 50000, 1};
  L3.j[1] = L3.j[0]; L3.j[2] = L3.j[0]; L3.j[3] = L3.j[0]; L3.j[4] = L3.j[0]; L3.j[5] = L3.j[0];

  hop_b_k<<<dim3(1250, 6), 256, 0, stream>>>(L0);
  hop_b_k<<<dim3(1250, 5), 256, 0, stream>>>(L1);
  hop_b_k<<<dim3(1250, 2), 256, 0, stream>>>(L2);
  hop_b_k<<<dim3(782, 1), 256, 0, stream>>>(L3);

  // ---- fusion (both layers batched) ---------------------------------------
  hipMemsetAsync(ZT0, 0, (size_t)192 * NP0 * 2, stream);
  hipMemsetAsync(ZT1, 0, (size_t)192 * NP1 * 2, stream);

  {
    GemmBatch fb = {};
    for (int p = 0; p < 3; ++p) {
      fb.j[p]     = {OUTSu + (size_t)p * 50000 * 128, FCT + (size_t)p * 64 * 128, nullptr,
                     Z0 + p * 64, ZT0 + (size_t)p * 64 * NP0, 50000, NP0};
      fb.j[p + 3] = {OUTSi + (size_t)p * 80000 * 128, FCT + (size_t)(3 + p) * 64 * 128, nullptr,
                     Z1 + p * 64, ZT1 + (size_t)p * 64 * NP1, 80000, NP1};
    }
    gemm_b_k<128, 64, ACT_TANH, 0, false, true>
        <<<dim3(1250, 6), 256, 0, stream>>>(fb, 128, 192);
  }

  gram_k<<<dim3(GRAM_NKB, 6), 256, 0, stream>>>(ZT0, ZT1, NP0, NP1, G);

  {
    VFJob j0 = {Z0, VT, VRT, FCRT, OUTSu, out, RE + 0, 50000};
    VFJob j1 = {Z1, VT + (size_t)128 * 192, VRT + (size_t)192 * 128, FCRT + (size_t)3 * 128 * 64,
                OUTSi, out + 6400000, RE + 1, 80000};
    vfuse_k<<<dim3(1250, 2), 256, 0, stream>>>(j0, j1);
  }

  loss_k<<<1, 256, 0, stream>>>(G, RE, out + 16640000);
}